// Round 18
// baseline (193.978 us; speedup 1.0000x reference)
//
#include <hip/hip_runtime.h>
#include <stdint.h>

typedef __bf16 bf16;
typedef __bf16 bf16x4 __attribute__((ext_vector_type(4)));
typedef __bf16 bf16x8 __attribute__((ext_vector_type(8)));
typedef float f32x4 __attribute__((ext_vector_type(4)));

// ------------------------------------- unified cast / transpose-cast kernel
// Tiles [128 r][64 c] -> dstT write runs of 256B (16 lanes x 16B, one row).
// Flat grid 2816 blocks:
//   [0,2048):    x slots z=0..3 (4096x1024, 32x16) -> dst (reg path) + dstT
//   [2048,2560): W slots z=4..7 (1024x1024,  8x16) -> dstT only
//   [2560,2816): P slots z=8..9 (4096x256,  32x4)  -> dstT only
// LDS: bf16 tb[128][72] (18.4KB, keeps occupancy).  Store: 16B/lane at
// col-group (t&7)^(r&7) -> 8 lanes/4-bank-group = the 16B/lane floor.
// Gather: 16 lanes of an output row read the SAME LDS word (broadcast, free);
// 4 row-groups/wave land on distinct banks.
struct XP {
  const float* src[10];
  bf16* dst[10];
  bf16* dstT[10];
  int R[10], C[10];
};

__global__ __launch_bounds__(256) void k_xpose(XP a) {
  const int bid = blockIdx.x;
  int z, bx, by;
  if (bid < 2048) {
    z = bid >> 9; int r = bid & 511; by = r >> 4; bx = r & 15;
  } else if (bid < 2560) {
    int r = bid - 2048; z = 4 + (r >> 7); r &= 127; by = r >> 4; bx = r & 15;
  } else {
    int r = bid - 2560; z = 8 + (r >> 7); r &= 127; by = r >> 2; bx = r & 3;
  }
  const int R = a.R[z], C = a.C[z];
  const float* __restrict__ src = a.src[z];
  bf16* __restrict__ dst = a.dst[z];
  bf16* __restrict__ dstT = a.dstT[z];
  const int r0 = by * 128, c0 = bx * 64;
  __shared__ bf16 tb[128][72];  // row stride 144B = 9x16B (16B-aligned)
  const int t = threadIdx.x;

  // load: 4 passes, 2x float4/lane (8 lanes x 32B per row); convert once;
  // reg-direct dst store (128B runs) + swizzled LDS bf16 store.
  const int rr = t >> 3, c8 = (t & 7) * 8;
#pragma unroll
  for (int i = 0; i < 4; ++i) {
    const int r = i * 32 + rr;
    const float* sp = &src[(size_t)(r0 + r) * C + c0 + c8];
    float4 v0 = *reinterpret_cast<const float4*>(sp);
    float4 v1 = *reinterpret_cast<const float4*>(sp + 4);
    bf16x8 o;
    o[0] = (bf16)v0.x; o[1] = (bf16)v0.y; o[2] = (bf16)v0.z; o[3] = (bf16)v0.w;
    o[4] = (bf16)v1.x; o[5] = (bf16)v1.y; o[6] = (bf16)v1.z; o[7] = (bf16)v1.w;
    if (dst)
      *reinterpret_cast<bf16x8*>(&dst[(size_t)(r0 + r) * C + c0 + c8]) = o;
    const int gs = (((t & 7) ^ (r & 7)) << 3);
    *reinterpret_cast<bf16x8*>(&tb[r][gs]) = o;
  }
  __syncthreads();

  // dstT: q -> out-row c=q>>4 (0..63), chunk u8=q&15; 16 lanes share c ->
  // 256B contiguous stores.  Gather col swizzle matches the store.
#pragma unroll
  for (int h = 0; h < 4; ++h) {
    const int q = h * 256 + t;
    const int c = q >> 4, u8 = q & 15;
    bf16x8 o;
#pragma unroll
    for (int j = 0; j < 8; ++j) {
      const int row = u8 * 8 + j;
      o[j] = tb[row][(((c >> 3) ^ (row & 7)) << 3) + (c & 7)];
    }
    *reinterpret_cast<bf16x8*>(&dstT[(size_t)(c0 + c) * R + r0 + u8 * 8]) = o;
  }
}

#define GLL(gp, lp)                                              \
  __builtin_amdgcn_global_load_lds(                              \
      (const __attribute__((address_space(1))) void*)(gp),       \
      (__attribute__((address_space(3))) void*)(lp), 16, 0, 0)

// ---------------------------------------------------------------- NT bf16 GEMM
template <typename CT>
__global__ __launch_bounds__(256) void k_gemm_nt(
    const bf16* __restrict__ A, const bf16* __restrict__ Bt,
    const bf16* __restrict__ Bt2, CT* __restrict__ C,
    int lda, int ldb, int ldc, int Kd, long sA, long sB, long sC,
    int zmod, long kOff, int mbSplit, CT* __restrict__ Ct, long sCt, int ldct,
    int mbT) {
  int zb = blockIdx.z, kc = 0;
  if (zmod > 1) { zb = blockIdx.z / zmod; kc = blockIdx.z % zmod; }
  const int mb = blockIdx.x, nb = blockIdx.y;
  A += (long)zb * sA + (long)kc * kOff;
  const bf16* Bsel = (mb < mbSplit) ? Bt : Bt2;
  Bsel += (long)zb * sB + (long)kc * kOff;
  C += (long)blockIdx.z * sC;
  Ct += (long)blockIdx.z * sCt;

  __shared__ bf16 As[2][128 * 32];
  __shared__ bf16 Bs[2][128 * 32];
  const int tid = threadIdx.x, lane = tid & 63, wid = tid >> 6;
  const int wr = wid >> 1, wc = wid & 1;
  const int srow = lane >> 2;
  const int skk = (((lane & 3) ^ ((srow >> 1) & 3)) << 3);

  f32x4 acc[4][4] = {};
  const bf16* Abase = A + (long)mb * 128 * lda;
  const bf16* Bbase = Bsel + (long)nb * 128 * ldb;

  auto stage = [&](int buf, int k0) {
#pragma unroll
    for (int i = 0; i < 2; ++i) {
      const int ch = wid * 2 + i;
      const int row = ch * 16 + srow;
      GLL(Abase + (long)row * lda + k0 + skk, &As[buf][ch * 512]);
      GLL(Bbase + (long)row * ldb + k0 + skk, &Bs[buf][ch * 512]);
    }
  };

  stage(0, 0);
  const int nk = Kd >> 5;
  for (int kt = 0; kt < nk; ++kt) {
    const int cur = kt & 1;
    if (kt + 1 < nk) stage(cur ^ 1, (kt + 1) << 5);
    __syncthreads();
    const int slot = lane >> 4;
    bf16x8 af[4], bb[4];
#pragma unroll
    for (int i = 0; i < 4; ++i) {
      const int r = wr * 64 + i * 16 + (lane & 15);
      af[i] = *reinterpret_cast<const bf16x8*>(
          reinterpret_cast<const char*>(As[cur]) + r * 64 +
          ((slot ^ ((r >> 1) & 3)) << 4));
      const int c = wc * 64 + i * 16 + (lane & 15);
      bb[i] = *reinterpret_cast<const bf16x8*>(
          reinterpret_cast<const char*>(Bs[cur]) + c * 64 +
          ((slot ^ ((c >> 1) & 3)) << 4));
    }
#pragma unroll
    for (int i = 0; i < 4; ++i)
#pragma unroll
      for (int j = 0; j < 4; ++j)
        acc[i][j] =
            __builtin_amdgcn_mfma_f32_16x16x32_bf16(af[i], bb[j], acc[i][j], 0, 0, 0);
    __syncthreads();
  }

  const long row0 = (long)mb * 128 + wr * 64 + ((lane >> 4) << 2);
  const int col0 = nb * 128 + wc * 64 + (lane & 15);
  if (mb >= mbT) {
    const long r0 = row0 - (long)mbT * 128;
#pragma unroll
    for (int i = 0; i < 4; ++i)
#pragma unroll
      for (int j = 0; j < 4; ++j)
#pragma unroll
        for (int r = 0; r < 4; ++r)
          Ct[(long)(col0 + j * 16) * ldct + (r0 + i * 16 + r)] = (CT)acc[i][j][r];
  } else {
#pragma unroll
    for (int i = 0; i < 4; ++i)
#pragma unroll
      for (int r = 0; r < 4; ++r)
#pragma unroll
        for (int j = 0; j < 4; ++j)
          C[(row0 + i * 16 + r) * ldc + (col0 + j * 16)] = (CT)acc[i][j][r];
  }
}

// ------------------------------------------- 256x256 8-phase GEMM (m201-style)
#define BARR __builtin_amdgcn_s_barrier()
#define SB0 __builtin_amdgcn_sched_barrier(0)
#define LGKM0                                             \
  asm volatile("s_waitcnt lgkmcnt(0)" ::: "memory");      \
  __builtin_amdgcn_sched_barrier(0)
#define VMC4 asm volatile("s_waitcnt vmcnt(4)" ::: "memory")

#define RDA(buf, ih)                                        \
  _Pragma("unroll") for (int i_ = 0; i_ < 4; ++i_)          \
  _Pragma("unroll") for (int k_ = 0; k_ < 2; ++k_)          \
      af[i_][k_] = ldaf(buf, (ih) * 4 + i_, k_)

#define RDB(buf, nh, dst)                                   \
  _Pragma("unroll") for (int n_ = 0; n_ < 2; ++n_)          \
  _Pragma("unroll") for (int k_ = 0; k_ < 2; ++k_)          \
      dst[n_][k_] = ldbf(buf, (nh) * 2 + n_, k_)

#define MM(ih, nh, B)                                                         \
  __builtin_amdgcn_s_setprio(1);                                              \
  _Pragma("unroll") for (int k_ = 0; k_ < 2; ++k_)                            \
  _Pragma("unroll") for (int i_ = 0; i_ < 4; ++i_)                            \
  _Pragma("unroll") for (int n_ = 0; n_ < 2; ++n_)                            \
      acc[(ih) * 4 + i_][(nh) * 2 + n_] =                                     \
          __builtin_amdgcn_mfma_f32_16x16x32_bf16(                            \
              af[i_][k_], B[n_][k_], acc[(ih) * 4 + i_][(nh) * 2 + n_], 0, 0, \
              0);                                                             \
  __builtin_amdgcn_s_setprio(0)

template <typename CT>
__global__ __launch_bounds__(512, 2) void k_gemm256(
    const bf16* __restrict__ A, const bf16* __restrict__ Bt, CT* __restrict__ C,
    int NT) {
  const int b0 = blockIdx.x;
  const int swz = (b0 & 7) * 32 + (b0 >> 3);
  const int mb = swz >> 2, nb = swz & 3;

  const int tid = threadIdx.x, lane = tid & 63, wid = tid >> 6;
  const int wr = wid >> 2, wc = wid & 3;
  const int x = lane & 15, g = lane >> 4;
  __shared__ bf16 Asl[2][16384];
  __shared__ bf16 Bsl[2][16384];

  const bf16* Ab = A + (long)mb * 256 * 1024;
  const bf16* Bb = Bt + (long)nb * 256 * 1024;
  const int srow8 = lane >> 3;
  const int skk = (((lane & 7) ^ srow8) << 3);

  auto stage = [&](int buf, int T, int j) {
    const bf16* src = (j < 2) ? Ab : Bb;
    bf16* db = ((j < 2) ? Asl[buf] : Bsl[buf]) + (j & 1) * 8192;
    const long ko = (long)T * 64 + skk;
#pragma unroll
    for (int i2 = 0; i2 < 2; ++i2) {
      const int c = wid * 2 + i2;
      GLL(src + (long)((j & 1) * 128 + c * 8 + srow8) * 1024 + ko, db + c * 512);
    }
  };
  auto ldaf = [&](int buf, int i, int s) {
    const int r = wr * 128 + i * 16 + x;
    return *reinterpret_cast<const bf16x8*>(
        reinterpret_cast<const char*>(Asl[buf]) + r * 128 +
        ((((s << 2) | g) ^ (r & 7)) << 4));
  };
  auto ldbf = [&](int buf, int n, int s) {
    const int c = wc * 64 + n * 16 + x;
    return *reinterpret_cast<const bf16x8*>(
        reinterpret_cast<const char*>(Bsl[buf]) + c * 128 +
        ((((s << 2) | g) ^ (c & 7)) << 4));
  };

  f32x4 acc[8][4] = {};
  bf16x8 af[4][2], bn01[2][2], bn23[2][2];

  stage(0, 0, 0); stage(0, 0, 1); stage(0, 0, 2); stage(0, 0, 3);
  stage(1, 1, 2); stage(1, 1, 3);
  VMC4;

  const int nit = NT >> 1;
  for (int it = 0; it < nit; ++it) {
    const int T = 2 * it;
    const int Tp1 = T + 1, Tp2 = (T + 2) % NT, Tp3 = (T + 3) % NT;
    // ph1 (publish T -> buf0)
    BARR; SB0;
    RDA(0, 0); RDB(0, 0, bn01);
    LGKM0;
    MM(0, 0, bn01);
    RDB(0, 1, bn23); stage(1, Tp1, 0);
    // ph2
    BARR; SB0; LGKM0;
    MM(0, 1, bn23);
    RDA(0, 1); stage(1, Tp1, 1);
    // ph3
    BARR; SB0; LGKM0;
    MM(1, 0, bn01);
    stage(0, Tp2, 2);
    // ph4
    BARR; SB0; LGKM0;
    MM(1, 1, bn23);
    stage(0, Tp2, 3);
    VMC4;
    // ph5 (publish T+1 -> buf1)
    BARR; SB0;
    RDA(1, 0); RDB(1, 0, bn01);
    LGKM0;
    MM(0, 0, bn01);
    RDB(1, 1, bn23); stage(0, Tp2, 0);
    // ph6
    BARR; SB0; LGKM0;
    MM(0, 1, bn23);
    RDA(1, 1); stage(0, Tp2, 1);
    // ph7
    BARR; SB0; LGKM0;
    MM(1, 0, bn01);
    stage(1, Tp3, 2);
    // ph8
    BARR; SB0; LGKM0;
    MM(1, 1, bn23);
    stage(1, Tp3, 3);
    VMC4;
  }

  const long row0 = (long)mb * 256 + wr * 128 + (g << 2);
  const int col0 = nb * 256 + wc * 64 + x;
#pragma unroll
  for (int i = 0; i < 8; ++i)
#pragma unroll
    for (int r = 0; r < 4; ++r)
#pragma unroll
      for (int n = 0; n < 4; ++n)
        C[(row0 + i * 16 + r) * 1024 + (col0 + n * 16)] = (CT)acc[i][n][r];
}

// ---------------------------------------------- split-K partial reduce (4 -> 1)
__global__ __launch_bounds__(256) void k_red4(const float* __restrict__ p,
                                              bf16* __restrict__ out) {
  const int i = blockIdx.x * 256 + threadIdx.x;
  const int SL = 512 * 1024;
  const int b = (i * 4) / SL;
  const int e = (i * 4) % SL;
  const float* base = p + (size_t)b * 4 * SL + e;
  float4 s0 = *reinterpret_cast<const float4*>(base);
  float4 s1 = *reinterpret_cast<const float4*>(base + SL);
  float4 s2 = *reinterpret_cast<const float4*>(base + 2 * SL);
  float4 s3 = *reinterpret_cast<const float4*>(base + 3 * SL);
  bf16x4 o;
  o[0] = (bf16)(s0.x + s1.x + s2.x + s3.x);
  o[1] = (bf16)(s0.y + s1.y + s2.y + s3.y);
  o[2] = (bf16)(s0.z + s1.z + s2.z + s3.z);
  o[3] = (bf16)(s0.w + s1.w + s2.w + s3.w);
  *reinterpret_cast<bf16x4*>(out + (size_t)b * SL + e) = o;
}

// ------------------------------------------------------------- fused attention
// grid (32 lt2, 16 h, 4 b), 512 thr = 8 waves / 128 q-rows per block.
__global__ __launch_bounds__(512) void k_attn(const bf16* __restrict__ q,
                                              const bf16* __restrict__ kc,
                                              const bf16* __restrict__ vT,
                                              bf16* __restrict__ aout) {
  const int lt = blockIdx.x, h = blockIdx.y, b = blockIdx.z;
  const int tid = threadIdx.x, lane = tid & 63, wid = tid >> 6;
  const int x = lane & 15, g = lane >> 4;
  __shared__ bf16 smem[32768];  // 64 KB
  bf16* Ks = smem;
  bf16* Vs = smem + 16384;

  const bf16* kb = kc + ((long)b * 256) * 1024 + h * 64;
#pragma unroll
  for (int it = 0; it < 4; ++it) {
    const int lin = it * 512 + tid;
    const int k = lin >> 3, s = lin & 7;
    const int rel = k & 31;
    const int pk = (k & ~31) | ((rel & 1) << 4) | ((rel >> 3) << 2) | ((rel >> 1) & 3);
    bf16x8 v = *reinterpret_cast<const bf16x8*>(kb + (long)k * 1024 + s * 8);
    *reinterpret_cast<bf16x8*>(reinterpret_cast<char*>(Ks) + pk * 128 +
                               ((s ^ (pk & 7)) << 4)) = v;
  }
  const bf16* vb = vT + (long)b * 1024 * 256 + (long)h * 64 * 256;
#pragma unroll
  for (int it = 0; it < 4; ++it) {
    const int lin = it * 512 + tid;
    const int d = lin >> 5, s = lin & 31;
    bf16x8 v = *reinterpret_cast<const bf16x8*>(vb + (long)d * 256 + s * 8);
    *reinterpret_cast<bf16x8*>(reinterpret_cast<char*>(Vs) + d * 512 +
                               ((s ^ (d & 7)) << 4)) = v;
  }

  const long qrow0 = (long)b * 4096 + lt * 128 + wid * 16;
  const bf16* qb = q + (qrow0 + x) * 1024 + h * 64;
  bf16x8 qf[2];
#pragma unroll
  for (int ks2 = 0; ks2 < 2; ++ks2)
    qf[ks2] = *reinterpret_cast<const bf16x8*>(qb + ks2 * 32 + g * 8);

  __syncthreads();

  f32x4 ln[16] = {};
  __builtin_amdgcn_s_setprio(1);
#pragma unroll
  for (int ks2 = 0; ks2 < 2; ++ks2) {
    const int slot = ks2 * 4 + g;
#pragma unroll
    for (int f = 0; f < 16; ++f) {
      const int row = f * 16 + x;
      bf16x8 kf = *reinterpret_cast<const bf16x8*>(
          reinterpret_cast<const char*>(Ks) + row * 128 + ((slot ^ (row & 7)) << 4));
      ln[f] = __builtin_amdgcn_mfma_f32_16x16x32_bf16(kf, qf[ks2], ln[f], 0, 0, 0);
    }
  }
  __builtin_amdgcn_s_setprio(0);

  float m = -1e30f;
#pragma unroll
  for (int f = 0; f < 16; ++f)
#pragma unroll
    for (int r = 0; r < 4; ++r) m = fmaxf(m, ln[f][r]);
  m = fmaxf(m, __shfl_xor(m, 16, 64));
  m = fmaxf(m, __shfl_xor(m, 32, 64));
  float sum = 0.f;
#pragma unroll
  for (int f = 0; f < 16; ++f)
#pragma unroll
    for (int r = 0; r < 4; ++r) {
      const float p = __expf((ln[f][r] - m) * 0.125f);
      ln[f][r] = p;
      sum += p;
    }
  sum += __shfl_xor(sum, 16, 64);
  sum += __shfl_xor(sum, 32, 64);
  const float inv = 1.f / sum;

  f32x4 oacc[4] = {};
  __builtin_amdgcn_s_setprio(1);
#pragma unroll
  for (int ks = 0; ks < 8; ++ks) {
    bf16x8 pa;
#pragma unroll
    for (int t = 0; t < 4; ++t) {
      pa[2 * t] = (bf16)ln[2 * ks][t];
      pa[2 * t + 1] = (bf16)ln[2 * ks + 1][t];
    }
    const int slot = ks * 4 + g;
#pragma unroll
    for (int nf = 0; nf < 4; ++nf) {
      const int d2 = nf * 16 + x;
      bf16x8 vv = *reinterpret_cast<const bf16x8*>(
          reinterpret_cast<const char*>(Vs) + d2 * 512 + ((slot ^ (d2 & 7)) << 4));
      oacc[nf] = __builtin_amdgcn_mfma_f32_16x16x32_bf16(pa, vv, oacc[nf], 0, 0, 0);
    }
  }
  __builtin_amdgcn_s_setprio(0);

  float invr[4];
#pragma unroll
  for (int r = 0; r < 4; ++r) invr[r] = __shfl(inv, 4 * g + r, 64);
  bf16* ob = aout + (qrow0 + 4 * g) * 1024 + h * 64 + x;
#pragma unroll
  for (int nf = 0; nf < 4; ++nf)
#pragma unroll
    for (int r = 0; r < 4; ++r)
      ob[(long)r * 1024 + nf * 16] = (bf16)(oacc[nf][r] * invr[r]);
}

// --------------------------------------------------------------------- launch
extern "C" void kernel_launch(void* const* d_in, const int* in_sizes, int n_in,
                              void* d_out, int out_size, void* d_ws, size_t ws_size,
                              hipStream_t stream) {
  const float* x  = (const float*)d_in[0];
  const float* Wq = (const float*)d_in[1];
  const float* Wk = (const float*)d_in[2];
  const float* Wv = (const float*)d_in[3];
  const float* Wo = (const float*)d_in[4];
  const float* Pk = (const float*)d_in[5];
  const float* Pv = (const float*)d_in[6];
  char* ws = (char*)d_ws;
  const long MB = 1024L * 1024;
  bf16* xbf = (bf16*)ws;
  bf16* XT  = (bf16*)(ws + 32 * MB);
  bf16* WqT = (bf16*)(ws + 64 * MB);
  bf16* WkT = (bf16*)(ws + 66 * MB);
  bf16* WvT = (bf16*)(ws + 68 * MB);
  bf16* WoT = (bf16*)(ws + 70 * MB);
  bf16* PT  = (bf16*)(ws + 72 * MB);
  float* XCp = (float*)(ws + 76 * MB);
  bf16* qbf = (bf16*)(ws + 76 * MB);
  bf16* XC  = (bf16*)(ws + 108 * MB);
  bf16* kcb = (bf16*)(ws + 112 * MB);
  bf16* vcT = (bf16*)(ws + 114 * MB);
  bf16* aout = xbf;
  const int BIG = 1 << 30;
  (void)in_sizes; (void)n_in; (void)out_size; (void)ws_size;

  // 1) all casts/transposes, exact flat grid (2816 blocks, 128x64 tiles)
  XP xp;
  for (int b = 0; b < 4; ++b) {
    xp.src[b] = x + (long)b * 4096 * 1024;
    xp.dst[b] = xbf + (long)b * 4096 * 1024;
    xp.dstT[b] = XT + (long)b * 1024 * 4096;
    xp.R[b] = 4096; xp.C[b] = 1024;
  }
  const float* wsrc[4] = {Wq, Wk, Wv, Wo};
  bf16* wdst[4] = {WqT, WkT, WvT, WoT};
  for (int i = 0; i < 4; ++i) {
    xp.src[4 + i] = wsrc[i];
    xp.dst[4 + i] = nullptr;
    xp.dstT[4 + i] = wdst[i];
    xp.R[4 + i] = 1024; xp.C[4 + i] = 1024;
  }
  xp.src[8] = Pk; xp.dst[8] = nullptr; xp.dstT[8] = PT;
  xp.R[8] = 4096; xp.C[8] = 256;
  xp.src[9] = Pv; xp.dst[9] = nullptr; xp.dstT[9] = PT + 256 * 4096;
  xp.R[9] = 4096; xp.C[9] = 256;
  k_xpose<<<dim3(2816), 256, 0, stream>>>(xp);

  // 2) XC split-K x4 partials + reduce
  k_gemm_nt<float><<<dim3(4, 8, 16), 256, 0, stream>>>(
      PT, XT, XT, XCp, 4096, 4096, 1024, 1024, 0, 1024L * 4096, 512L * 1024, 4, 1024,
      BIG, XCp, 0, 1024, BIG);
  k_red4<<<dim3(2048), 256, 0, stream>>>(XCp, XC);

  // 3) kc = XCk@Wk ; vcT = (XCv@Wv)^T
  k_gemm_nt<bf16><<<dim3(4, 8, 4), 256, 0, stream>>>(
      XC, WkT, WvT, kcb, 1024, 1024, 1024, 1024, 512L * 1024, 0, 256L * 1024, 1, 0, 2,
      vcT, 1024L * 256, 256, 2);

  // 4) Q = x @ Wq   (8-phase 256^2 kernel, NT = 16)
  k_gemm256<bf16><<<dim3(256), 512, 0, stream>>>(xbf, WqT, qbf, 16);

  // 5) attention
  k_attn<<<dim3(32, 16, 4), 512, 0, stream>>>(qbf, kcb, vcT, aout);

  // 6) out = aout @ Wo (fp32 out)
  k_gemm256<float><<<dim3(256), 512, 0, stream>>>(aout, WoT, (float*)d_out, 16);
}

// Round 19
// 191.277 us; speedup vs baseline: 1.0141x; 1.0141x over previous
//
#include <hip/hip_runtime.h>
#include <stdint.h>

typedef __bf16 bf16;
typedef __bf16 bf16x4 __attribute__((ext_vector_type(4)));
typedef __bf16 bf16x8 __attribute__((ext_vector_type(8)));
typedef float f32x4 __attribute__((ext_vector_type(4)));

// ------------------------------------- unified cast / transpose-cast kernel
// R15-proven tile math ([64][65] f32 LDS, 2-way-max banking), now 2 tiles
// per block (row-adjacent), software-pipelined: T1's global loads issue
// before T0's gather so the gather hides the load latency.  LDS unchanged
// (16.9KB) -> occupancy preserved.
// Flat grid 2816 blocks:
//   [0,2048):    x slots z=0..3 (4096x1024; 32 bypairs x 16 bx) -> dst+dstT
//   [2048,2560): W slots z=4..7 (1024x1024;  8 x 16)            -> dstT
//   [2560,2816): P slots z=8..9 (4096x256;  32 x 4)             -> dstT
struct XP {
  const float* src[10];
  bf16* dst[10];
  bf16* dstT[10];
  int R[10], C[10];
};

__global__ __launch_bounds__(256) void k_xpose(XP a) {
  const int bid = blockIdx.x;
  int z, bx, byp;
  if (bid < 2048) {
    z = bid >> 9; int r = bid & 511; byp = r >> 4; bx = r & 15;
  } else if (bid < 2560) {
    int r = bid - 2048; z = 4 + (r >> 7); r &= 127; byp = r >> 4; bx = r & 15;
  } else {
    int r = bid - 2560; z = 8 + (r >> 7); r &= 127; byp = r >> 2; bx = r & 3;
  }
  const int R = a.R[z], C = a.C[z];
  const float* __restrict__ src = a.src[z];
  bf16* __restrict__ dst = a.dst[z];
  bf16* __restrict__ dstT = a.dstT[z];
  const int r0a = byp * 128, r0b = r0a + 64, c0 = bx * 64;
  __shared__ float tile[64][65];
  const int t = threadIdx.x;
  const int rr = t >> 3, c8 = (t & 7) * 8;

  auto loadT = [&](int r0, float4* v) {
#pragma unroll
    for (int i = 0; i < 2; ++i) {
      const float* sp = &src[(size_t)(r0 + i * 32 + rr) * C + c0 + c8];
      v[2 * i] = *reinterpret_cast<const float4*>(sp);
      v[2 * i + 1] = *reinterpret_cast<const float4*>(sp + 4);
    }
  };
  auto stLDSdst = [&](int r0, const float4* v) {
#pragma unroll
    for (int i = 0; i < 2; ++i) {
      const int r = i * 32 + rr;
      const float4 v0 = v[2 * i], v1 = v[2 * i + 1];
      tile[r][c8] = v0.x; tile[r][c8 + 1] = v0.y;
      tile[r][c8 + 2] = v0.z; tile[r][c8 + 3] = v0.w;
      tile[r][c8 + 4] = v1.x; tile[r][c8 + 5] = v1.y;
      tile[r][c8 + 6] = v1.z; tile[r][c8 + 7] = v1.w;
      if (dst) {
        bf16x8 o;
        o[0] = (bf16)v0.x; o[1] = (bf16)v0.y; o[2] = (bf16)v0.z; o[3] = (bf16)v0.w;
        o[4] = (bf16)v1.x; o[5] = (bf16)v1.y; o[6] = (bf16)v1.z; o[7] = (bf16)v1.w;
        *reinterpret_cast<bf16x8*>(&dst[(size_t)(r0 + r) * C + c0 + c8]) = o;
      }
    }
  };
  auto gatherT = [&](int r0) {
#pragma unroll
    for (int h = 0; h < 2; ++h) {
      const int q = h * 256 + t;
      const int c = q >> 3, u = (q & 7) * 8;
      bf16x8 o;
#pragma unroll
      for (int j = 0; j < 8; ++j) o[j] = (bf16)tile[u + j][c];
      *reinterpret_cast<bf16x8*>(&dstT[(size_t)(c0 + c) * R + r0 + u]) = o;
    }
  };

  float4 vA[4], vB[4];
  loadT(r0a, vA);
  stLDSdst(r0a, vA);
  __syncthreads();
  loadT(r0b, vB);     // issue early: gather below runs under this latency
  gatherT(r0a);
  __syncthreads();    // all waves done reading tile
  stLDSdst(r0b, vB);
  __syncthreads();
  gatherT(r0b);
}

#define GLL(gp, lp)                                              \
  __builtin_amdgcn_global_load_lds(                              \
      (const __attribute__((address_space(1))) void*)(gp),       \
      (__attribute__((address_space(3))) void*)(lp), 16, 0, 0)

// ---------------------------------------------------------------- NT bf16 GEMM
template <typename CT>
__global__ __launch_bounds__(256) void k_gemm_nt(
    const bf16* __restrict__ A, const bf16* __restrict__ Bt,
    const bf16* __restrict__ Bt2, CT* __restrict__ C,
    int lda, int ldb, int ldc, int Kd, long sA, long sB, long sC,
    int zmod, long kOff, int mbSplit, CT* __restrict__ Ct, long sCt, int ldct,
    int mbT) {
  int zb = blockIdx.z, kc = 0;
  if (zmod > 1) { zb = blockIdx.z / zmod; kc = blockIdx.z % zmod; }
  const int mb = blockIdx.x, nb = blockIdx.y;
  A += (long)zb * sA + (long)kc * kOff;
  const bf16* Bsel = (mb < mbSplit) ? Bt : Bt2;
  Bsel += (long)zb * sB + (long)kc * kOff;
  C += (long)blockIdx.z * sC;
  Ct += (long)blockIdx.z * sCt;

  __shared__ bf16 As[2][128 * 32];
  __shared__ bf16 Bs[2][128 * 32];
  const int tid = threadIdx.x, lane = tid & 63, wid = tid >> 6;
  const int wr = wid >> 1, wc = wid & 1;
  const int srow = lane >> 2;
  const int skk = (((lane & 3) ^ ((srow >> 1) & 3)) << 3);

  f32x4 acc[4][4] = {};
  const bf16* Abase = A + (long)mb * 128 * lda;
  const bf16* Bbase = Bsel + (long)nb * 128 * ldb;

  auto stage = [&](int buf, int k0) {
#pragma unroll
    for (int i = 0; i < 2; ++i) {
      const int ch = wid * 2 + i;
      const int row = ch * 16 + srow;
      GLL(Abase + (long)row * lda + k0 + skk, &As[buf][ch * 512]);
      GLL(Bbase + (long)row * ldb + k0 + skk, &Bs[buf][ch * 512]);
    }
  };

  stage(0, 0);
  const int nk = Kd >> 5;
  for (int kt = 0; kt < nk; ++kt) {
    const int cur = kt & 1;
    if (kt + 1 < nk) stage(cur ^ 1, (kt + 1) << 5);
    __syncthreads();
    const int slot = lane >> 4;
    bf16x8 af[4], bb[4];
#pragma unroll
    for (int i = 0; i < 4; ++i) {
      const int r = wr * 64 + i * 16 + (lane & 15);
      af[i] = *reinterpret_cast<const bf16x8*>(
          reinterpret_cast<const char*>(As[cur]) + r * 64 +
          ((slot ^ ((r >> 1) & 3)) << 4));
      const int c = wc * 64 + i * 16 + (lane & 15);
      bb[i] = *reinterpret_cast<const bf16x8*>(
          reinterpret_cast<const char*>(Bs[cur]) + c * 64 +
          ((slot ^ ((c >> 1) & 3)) << 4));
    }
#pragma unroll
    for (int i = 0; i < 4; ++i)
#pragma unroll
      for (int j = 0; j < 4; ++j)
        acc[i][j] =
            __builtin_amdgcn_mfma_f32_16x16x32_bf16(af[i], bb[j], acc[i][j], 0, 0, 0);
    __syncthreads();
  }

  const long row0 = (long)mb * 128 + wr * 64 + ((lane >> 4) << 2);
  const int col0 = nb * 128 + wc * 64 + (lane & 15);
  if (mb >= mbT) {
    const long r0 = row0 - (long)mbT * 128;
#pragma unroll
    for (int i = 0; i < 4; ++i)
#pragma unroll
      for (int j = 0; j < 4; ++j)
#pragma unroll
        for (int r = 0; r < 4; ++r)
          Ct[(long)(col0 + j * 16) * ldct + (r0 + i * 16 + r)] = (CT)acc[i][j][r];
  } else {
#pragma unroll
    for (int i = 0; i < 4; ++i)
#pragma unroll
      for (int r = 0; r < 4; ++r)
#pragma unroll
        for (int j = 0; j < 4; ++j)
          C[(row0 + i * 16 + r) * ldc + (col0 + j * 16)] = (CT)acc[i][j][r];
  }
}

// ------------------------------------------- 256x256 8-phase GEMM (m201-style)
#define BARR __builtin_amdgcn_s_barrier()
#define SB0 __builtin_amdgcn_sched_barrier(0)
#define LGKM0                                             \
  asm volatile("s_waitcnt lgkmcnt(0)" ::: "memory");      \
  __builtin_amdgcn_sched_barrier(0)
#define VMC4 asm volatile("s_waitcnt vmcnt(4)" ::: "memory")

#define RDA(buf, ih)                                        \
  _Pragma("unroll") for (int i_ = 0; i_ < 4; ++i_)          \
  _Pragma("unroll") for (int k_ = 0; k_ < 2; ++k_)          \
      af[i_][k_] = ldaf(buf, (ih) * 4 + i_, k_)

#define RDB(buf, nh, dst)                                   \
  _Pragma("unroll") for (int n_ = 0; n_ < 2; ++n_)          \
  _Pragma("unroll") for (int k_ = 0; k_ < 2; ++k_)          \
      dst[n_][k_] = ldbf(buf, (nh) * 2 + n_, k_)

#define MM(ih, nh, B)                                                         \
  __builtin_amdgcn_s_setprio(1);                                              \
  _Pragma("unroll") for (int k_ = 0; k_ < 2; ++k_)                            \
  _Pragma("unroll") for (int i_ = 0; i_ < 4; ++i_)                            \
  _Pragma("unroll") for (int n_ = 0; n_ < 2; ++n_)                            \
      acc[(ih) * 4 + i_][(nh) * 2 + n_] =                                     \
          __builtin_amdgcn_mfma_f32_16x16x32_bf16(                            \
              af[i_][k_], B[n_][k_], acc[(ih) * 4 + i_][(nh) * 2 + n_], 0, 0, \
              0);                                                             \
  __builtin_amdgcn_s_setprio(0)

template <typename CT>
__global__ __launch_bounds__(512, 2) void k_gemm256(
    const bf16* __restrict__ A, const bf16* __restrict__ Bt, CT* __restrict__ C,
    int NT) {
  const int b0 = blockIdx.x;
  const int swz = (b0 & 7) * 32 + (b0 >> 3);
  const int mb = swz >> 2, nb = swz & 3;

  const int tid = threadIdx.x, lane = tid & 63, wid = tid >> 6;
  const int wr = wid >> 2, wc = wid & 3;
  const int x = lane & 15, g = lane >> 4;
  __shared__ bf16 Asl[2][16384];
  __shared__ bf16 Bsl[2][16384];

  const bf16* Ab = A + (long)mb * 256 * 1024;
  const bf16* Bb = Bt + (long)nb * 256 * 1024;
  const int srow8 = lane >> 3;
  const int skk = (((lane & 7) ^ srow8) << 3);

  auto stage = [&](int buf, int T, int j) {
    const bf16* src = (j < 2) ? Ab : Bb;
    bf16* db = ((j < 2) ? Asl[buf] : Bsl[buf]) + (j & 1) * 8192;
    const long ko = (long)T * 64 + skk;
#pragma unroll
    for (int i2 = 0; i2 < 2; ++i2) {
      const int c = wid * 2 + i2;
      GLL(src + (long)((j & 1) * 128 + c * 8 + srow8) * 1024 + ko, db + c * 512);
    }
  };
  auto ldaf = [&](int buf, int i, int s) {
    const int r = wr * 128 + i * 16 + x;
    return *reinterpret_cast<const bf16x8*>(
        reinterpret_cast<const char*>(Asl[buf]) + r * 128 +
        ((((s << 2) | g) ^ (r & 7)) << 4));
  };
  auto ldbf = [&](int buf, int n, int s) {
    const int c = wc * 64 + n * 16 + x;
    return *reinterpret_cast<const bf16x8*>(
        reinterpret_cast<const char*>(Bsl[buf]) + c * 128 +
        ((((s << 2) | g) ^ (c & 7)) << 4));
  };

  f32x4 acc[8][4] = {};
  bf16x8 af[4][2], bn01[2][2], bn23[2][2];

  stage(0, 0, 0); stage(0, 0, 1); stage(0, 0, 2); stage(0, 0, 3);
  stage(1, 1, 2); stage(1, 1, 3);
  VMC4;

  const int nit = NT >> 1;
  for (int it = 0; it < nit; ++it) {
    const int T = 2 * it;
    const int Tp1 = T + 1, Tp2 = (T + 2) % NT, Tp3 = (T + 3) % NT;
    // ph1 (publish T -> buf0)
    BARR; SB0;
    RDA(0, 0); RDB(0, 0, bn01);
    LGKM0;
    MM(0, 0, bn01);
    RDB(0, 1, bn23); stage(1, Tp1, 0);
    // ph2
    BARR; SB0; LGKM0;
    MM(0, 1, bn23);
    RDA(0, 1); stage(1, Tp1, 1);
    // ph3
    BARR; SB0; LGKM0;
    MM(1, 0, bn01);
    stage(0, Tp2, 2);
    // ph4
    BARR; SB0; LGKM0;
    MM(1, 1, bn23);
    stage(0, Tp2, 3);
    VMC4;
    // ph5 (publish T+1 -> buf1)
    BARR; SB0;
    RDA(1, 0); RDB(1, 0, bn01);
    LGKM0;
    MM(0, 0, bn01);
    RDB(1, 1, bn23); stage(0, Tp2, 0);
    // ph6
    BARR; SB0; LGKM0;
    MM(0, 1, bn23);
    RDA(1, 1); stage(0, Tp2, 1);
    // ph7
    BARR; SB0; LGKM0;
    MM(1, 0, bn01);
    stage(1, Tp3, 2);
    // ph8
    BARR; SB0; LGKM0;
    MM(1, 1, bn23);
    stage(1, Tp3, 3);
    VMC4;
  }

  const long row0 = (long)mb * 256 + wr * 128 + (g << 2);
  const int col0 = nb * 256 + wc * 64 + x;
#pragma unroll
  for (int i = 0; i < 8; ++i)
#pragma unroll
    for (int r = 0; r < 4; ++r)
#pragma unroll
      for (int n = 0; n < 4; ++n)
        C[(row0 + i * 16 + r) * 1024 + (col0 + n * 16)] = (CT)acc[i][n][r];
}

// ---------------------------------------------- split-K partial reduce (4 -> 1)
__global__ __launch_bounds__(256) void k_red4(const float* __restrict__ p,
                                              bf16* __restrict__ out) {
  const int i = blockIdx.x * 256 + threadIdx.x;
  const int SL = 512 * 1024;
  const int b = (i * 4) / SL;
  const int e = (i * 4) % SL;
  const float* base = p + (size_t)b * 4 * SL + e;
  float4 s0 = *reinterpret_cast<const float4*>(base);
  float4 s1 = *reinterpret_cast<const float4*>(base + SL);
  float4 s2 = *reinterpret_cast<const float4*>(base + 2 * SL);
  float4 s3 = *reinterpret_cast<const float4*>(base + 3 * SL);
  bf16x4 o;
  o[0] = (bf16)(s0.x + s1.x + s2.x + s3.x);
  o[1] = (bf16)(s0.y + s1.y + s2.y + s3.y);
  o[2] = (bf16)(s0.z + s1.z + s2.z + s3.z);
  o[3] = (bf16)(s0.w + s1.w + s2.w + s3.w);
  *reinterpret_cast<bf16x4*>(out + (size_t)b * SL + e) = o;
}

// ------------------------------------------------------------- fused attention
// grid (32 lt2, 16 h, 4 b), 512 thr = 8 waves / 128 q-rows per block.
__global__ __launch_bounds__(512) void k_attn(const bf16* __restrict__ q,
                                              const bf16* __restrict__ kc,
                                              const bf16* __restrict__ vT,
                                              bf16* __restrict__ aout) {
  const int lt = blockIdx.x, h = blockIdx.y, b = blockIdx.z;
  const int tid = threadIdx.x, lane = tid & 63, wid = tid >> 6;
  const int x = lane & 15, g = lane >> 4;
  __shared__ bf16 smem[32768];  // 64 KB
  bf16* Ks = smem;
  bf16* Vs = smem + 16384;

  const bf16* kb = kc + ((long)b * 256) * 1024 + h * 64;
#pragma unroll
  for (int it = 0; it < 4; ++it) {
    const int lin = it * 512 + tid;
    const int k = lin >> 3, s = lin & 7;
    const int rel = k & 31;
    const int pk = (k & ~31) | ((rel & 1) << 4) | ((rel >> 3) << 2) | ((rel >> 1) & 3);
    bf16x8 v = *reinterpret_cast<const bf16x8*>(kb + (long)k * 1024 + s * 8);
    *reinterpret_cast<bf16x8*>(reinterpret_cast<char*>(Ks) + pk * 128 +
                               ((s ^ (pk & 7)) << 4)) = v;
  }
  const bf16* vb = vT + (long)b * 1024 * 256 + (long)h * 64 * 256;
#pragma unroll
  for (int it = 0; it < 4; ++it) {
    const int lin = it * 512 + tid;
    const int d = lin >> 5, s = lin & 31;
    bf16x8 v = *reinterpret_cast<const bf16x8*>(vb + (long)d * 256 + s * 8);
    *reinterpret_cast<bf16x8*>(reinterpret_cast<char*>(Vs) + d * 512 +
                               ((s ^ (d & 7)) << 4)) = v;
  }

  const long qrow0 = (long)b * 4096 + lt * 128 + wid * 16;
  const bf16* qb = q + (qrow0 + x) * 1024 + h * 64;
  bf16x8 qf[2];
#pragma unroll
  for (int ks2 = 0; ks2 < 2; ++ks2)
    qf[ks2] = *reinterpret_cast<const bf16x8*>(qb + ks2 * 32 + g * 8);

  __syncthreads();

  f32x4 ln[16] = {};
  __builtin_amdgcn_s_setprio(1);
#pragma unroll
  for (int ks2 = 0; ks2 < 2; ++ks2) {
    const int slot = ks2 * 4 + g;
#pragma unroll
    for (int f = 0; f < 16; ++f) {
      const int row = f * 16 + x;
      bf16x8 kf = *reinterpret_cast<const bf16x8*>(
          reinterpret_cast<const char*>(Ks) + row * 128 + ((slot ^ (row & 7)) << 4));
      ln[f] = __builtin_amdgcn_mfma_f32_16x16x32_bf16(kf, qf[ks2], ln[f], 0, 0, 0);
    }
  }
  __builtin_amdgcn_s_setprio(0);

  float m = -1e30f;
#pragma unroll
  for (int f = 0; f < 16; ++f)
#pragma unroll
    for (int r = 0; r < 4; ++r) m = fmaxf(m, ln[f][r]);
  m = fmaxf(m, __shfl_xor(m, 16, 64));
  m = fmaxf(m, __shfl_xor(m, 32, 64));
  float sum = 0.f;
#pragma unroll
  for (int f = 0; f < 16; ++f)
#pragma unroll
    for (int r = 0; r < 4; ++r) {
      const float p = __expf((ln[f][r] - m) * 0.125f);
      ln[f][r] = p;
      sum += p;
    }
  sum += __shfl_xor(sum, 16, 64);
  sum += __shfl_xor(sum, 32, 64);
  const float inv = 1.f / sum;

  f32x4 oacc[4] = {};
  __builtin_amdgcn_s_setprio(1);
#pragma unroll
  for (int ks = 0; ks < 8; ++ks) {
    bf16x8 pa;
#pragma unroll
    for (int t = 0; t < 4; ++t) {
      pa[2 * t] = (bf16)ln[2 * ks][t];
      pa[2 * t + 1] = (bf16)ln[2 * ks + 1][t];
    }
    const int slot = ks * 4 + g;
#pragma unroll
    for (int nf = 0; nf < 4; ++nf) {
      const int d2 = nf * 16 + x;
      bf16x8 vv = *reinterpret_cast<const bf16x8*>(
          reinterpret_cast<const char*>(Vs) + d2 * 512 + ((slot ^ (d2 & 7)) << 4));
      oacc[nf] = __builtin_amdgcn_mfma_f32_16x16x32_bf16(pa, vv, oacc[nf], 0, 0, 0);
    }
  }
  __builtin_amdgcn_s_setprio(0);

  float invr[4];
#pragma unroll
  for (int r = 0; r < 4; ++r) invr[r] = __shfl(inv, 4 * g + r, 64);
  bf16* ob = aout + (qrow0 + 4 * g) * 1024 + h * 64 + x;
#pragma unroll
  for (int nf = 0; nf < 4; ++nf)
#pragma unroll
    for (int r = 0; r < 4; ++r)
      ob[(long)r * 1024 + nf * 16] = (bf16)(oacc[nf][r] * invr[r]);
}

// --------------------------------------------------------------------- launch
extern "C" void kernel_launch(void* const* d_in, const int* in_sizes, int n_in,
                              void* d_out, int out_size, void* d_ws, size_t ws_size,
                              hipStream_t stream) {
  const float* x  = (const float*)d_in[0];
  const float* Wq = (const float*)d_in[1];
  const float* Wk = (const float*)d_in[2];
  const float* Wv = (const float*)d_in[3];
  const float* Wo = (const float*)d_in[4];
  const float* Pk = (const float*)d_in[5];
  const float* Pv = (const float*)d_in[6];
  char* ws = (char*)d_ws;
  const long MB = 1024L * 1024;
  bf16* xbf = (bf16*)ws;
  bf16* XT  = (bf16*)(ws + 32 * MB);
  bf16* WqT = (bf16*)(ws + 64 * MB);
  bf16* WkT = (bf16*)(ws + 66 * MB);
  bf16* WvT = (bf16*)(ws + 68 * MB);
  bf16* WoT = (bf16*)(ws + 70 * MB);
  bf16* PT  = (bf16*)(ws + 72 * MB);
  float* XCp = (float*)(ws + 76 * MB);
  bf16* qbf = (bf16*)(ws + 76 * MB);
  bf16* XC  = (bf16*)(ws + 108 * MB);
  bf16* kcb = (bf16*)(ws + 112 * MB);
  bf16* vcT = (bf16*)(ws + 114 * MB);
  bf16* aout = xbf;
  const int BIG = 1 << 30;
  (void)in_sizes; (void)n_in; (void)out_size; (void)ws_size;

  // 1) all casts/transposes, 2816 blocks (2 row-adjacent 64x64 tiles each)
  XP xp;
  for (int b = 0; b < 4; ++b) {
    xp.src[b] = x + (long)b * 4096 * 1024;
    xp.dst[b] = xbf + (long)b * 4096 * 1024;
    xp.dstT[b] = XT + (long)b * 1024 * 4096;
    xp.R[b] = 4096; xp.C[b] = 1024;
  }
  const float* wsrc[4] = {Wq, Wk, Wv, Wo};
  bf16* wdst[4] = {WqT, WkT, WvT, WoT};
  for (int i = 0; i < 4; ++i) {
    xp.src[4 + i] = wsrc[i];
    xp.dst[4 + i] = nullptr;
    xp.dstT[4 + i] = wdst[i];
    xp.R[4 + i] = 1024; xp.C[4 + i] = 1024;
  }
  xp.src[8] = Pk; xp.dst[8] = nullptr; xp.dstT[8] = PT;
  xp.R[8] = 4096; xp.C[8] = 256;
  xp.src[9] = Pv; xp.dst[9] = nullptr; xp.dstT[9] = PT + 256 * 4096;
  xp.R[9] = 4096; xp.C[9] = 256;
  k_xpose<<<dim3(2816), 256, 0, stream>>>(xp);

  // 2) XC split-K x4 partials + reduce
  k_gemm_nt<float><<<dim3(4, 8, 16), 256, 0, stream>>>(
      PT, XT, XT, XCp, 4096, 4096, 1024, 1024, 0, 1024L * 4096, 512L * 1024, 4, 1024,
      BIG, XCp, 0, 1024, BIG);
  k_red4<<<dim3(2048), 256, 0, stream>>>(XCp, XC);

  // 3) kc = XCk@Wk ; vcT = (XCv@Wv)^T
  k_gemm_nt<bf16><<<dim3(4, 8, 4), 256, 0, stream>>>(
      XC, WkT, WvT, kcb, 1024, 1024, 1024, 1024, 512L * 1024, 0, 256L * 1024, 1, 0, 2,
      vcT, 1024L * 256, 256, 2);

  // 4) Q = x @ Wq   (8-phase 256^2 kernel, NT = 16)
  k_gemm256<bf16><<<dim3(256), 512, 0, stream>>>(xbf, WqT, qbf, 16);

  // 5) attention
  k_attn<<<dim3(32, 16, 4), 512, 0, stream>>>(qbf, kcb, vcT, aout);

  // 6) out = aout @ Wo (fp32 out)
  k_gemm256<float><<<dim3(256), 512, 0, stream>>>(aout, WoT, (float*)d_out, 16);
}

// Round 20
// 190.380 us; speedup vs baseline: 1.0189x; 1.0047x over previous
//
#include <hip/hip_runtime.h>
#include <stdint.h>

typedef __bf16 bf16;
typedef __bf16 bf16x4 __attribute__((ext_vector_type(4)));
typedef __bf16 bf16x8 __attribute__((ext_vector_type(8)));
typedef float f32x4 __attribute__((ext_vector_type(4)));

// ------------------------------------- unified cast / transpose-cast kernel
// (R17-proven best: single 64x64 tile, [64][65] f32 LDS, 2-way-max banking)
// Flat 1-D grid, exact block count:
//   [0,4096):   x slots z=0..3   (4096x1024) -> dst (direct reg path) + dstT
//   [4096,5120): W slots z=4..7  (1024x1024) -> dstT only
//   [5120,5632): P slots z=8..9  (4096x256)  -> dstT only
struct XP {
  const float* src[10];
  bf16* dst[10];
  bf16* dstT[10];
  int R[10], C[10];
};

__global__ __launch_bounds__(256) void k_xpose(XP a) {
  const int bid = blockIdx.x;
  int z, bx, by;
  if (bid < 4096) {
    z = bid >> 10; int r = bid & 1023; by = r >> 4; bx = r & 15;
  } else if (bid < 5120) {
    int r = bid - 4096; z = 4 + (r >> 8); r &= 255; by = r >> 4; bx = r & 15;
  } else {
    int r = bid - 5120; z = 8 + (r >> 8); r &= 255; by = r >> 2; bx = r & 3;
  }
  const int R = a.R[z], C = a.C[z];
  const float* __restrict__ src = a.src[z];
  bf16* __restrict__ dst = a.dst[z];
  bf16* __restrict__ dstT = a.dstT[z];
  const int r0 = by * 64, c0 = bx * 64;
  __shared__ float tile[64][65];
  const int t = threadIdx.x;

  const int rr = t >> 3, c8 = (t & 7) * 8;
#pragma unroll
  for (int i = 0; i < 2; ++i) {
    const int r = i * 32 + rr;
    const float* sp = &src[(size_t)(r0 + r) * C + c0 + c8];
    float4 v0 = *reinterpret_cast<const float4*>(sp);
    float4 v1 = *reinterpret_cast<const float4*>(sp + 4);
    tile[r][c8] = v0.x; tile[r][c8 + 1] = v0.y;
    tile[r][c8 + 2] = v0.z; tile[r][c8 + 3] = v0.w;
    tile[r][c8 + 4] = v1.x; tile[r][c8 + 5] = v1.y;
    tile[r][c8 + 6] = v1.z; tile[r][c8 + 7] = v1.w;
    if (dst) {
      bf16x8 o;
      o[0] = (bf16)v0.x; o[1] = (bf16)v0.y; o[2] = (bf16)v0.z; o[3] = (bf16)v0.w;
      o[4] = (bf16)v1.x; o[5] = (bf16)v1.y; o[6] = (bf16)v1.z; o[7] = (bf16)v1.w;
      *reinterpret_cast<bf16x8*>(&dst[(size_t)(r0 + r) * C + c0 + c8]) = o;
    }
  }
  __syncthreads();

#pragma unroll
  for (int h = 0; h < 2; ++h) {
    const int q = h * 256 + t;
    const int c = q >> 3, u = (q & 7) * 8;
    bf16x8 o;
#pragma unroll
    for (int j = 0; j < 8; ++j) o[j] = (bf16)tile[u + j][c];
    *reinterpret_cast<bf16x8*>(&dstT[(size_t)(c0 + c) * R + r0 + u]) = o;
  }
}

#define GLL(gp, lp)                                              \
  __builtin_amdgcn_global_load_lds(                              \
      (const __attribute__((address_space(1))) void*)(gp),       \
      (__attribute__((address_space(3))) void*)(lp), 16, 0, 0)

// ---------------------------------------------------------------- NT bf16 GEMM
template <typename CT>
__global__ __launch_bounds__(256) void k_gemm_nt(
    const bf16* __restrict__ A, const bf16* __restrict__ Bt,
    const bf16* __restrict__ Bt2, CT* __restrict__ C,
    int lda, int ldb, int ldc, int Kd, long sA, long sB, long sC,
    int zmod, long kOff, int mbSplit, CT* __restrict__ Ct, long sCt, int ldct,
    int mbT) {
  int zb = blockIdx.z, kc = 0;
  if (zmod > 1) { zb = blockIdx.z / zmod; kc = blockIdx.z % zmod; }
  const int mb = blockIdx.x, nb = blockIdx.y;
  A += (long)zb * sA + (long)kc * kOff;
  const bf16* Bsel = (mb < mbSplit) ? Bt : Bt2;
  Bsel += (long)zb * sB + (long)kc * kOff;
  C += (long)blockIdx.z * sC;
  Ct += (long)blockIdx.z * sCt;

  __shared__ bf16 As[2][128 * 32];
  __shared__ bf16 Bs[2][128 * 32];
  const int tid = threadIdx.x, lane = tid & 63, wid = tid >> 6;
  const int wr = wid >> 1, wc = wid & 1;
  const int srow = lane >> 2;
  const int skk = (((lane & 3) ^ ((srow >> 1) & 3)) << 3);

  f32x4 acc[4][4] = {};
  const bf16* Abase = A + (long)mb * 128 * lda;
  const bf16* Bbase = Bsel + (long)nb * 128 * ldb;

  auto stage = [&](int buf, int k0) {
#pragma unroll
    for (int i = 0; i < 2; ++i) {
      const int ch = wid * 2 + i;
      const int row = ch * 16 + srow;
      GLL(Abase + (long)row * lda + k0 + skk, &As[buf][ch * 512]);
      GLL(Bbase + (long)row * ldb + k0 + skk, &Bs[buf][ch * 512]);
    }
  };

  stage(0, 0);
  const int nk = Kd >> 5;
  for (int kt = 0; kt < nk; ++kt) {
    const int cur = kt & 1;
    if (kt + 1 < nk) stage(cur ^ 1, (kt + 1) << 5);
    __syncthreads();
    const int slot = lane >> 4;
    bf16x8 af[4], bb[4];
#pragma unroll
    for (int i = 0; i < 4; ++i) {
      const int r = wr * 64 + i * 16 + (lane & 15);
      af[i] = *reinterpret_cast<const bf16x8*>(
          reinterpret_cast<const char*>(As[cur]) + r * 64 +
          ((slot ^ ((r >> 1) & 3)) << 4));
      const int c = wc * 64 + i * 16 + (lane & 15);
      bb[i] = *reinterpret_cast<const bf16x8*>(
          reinterpret_cast<const char*>(Bs[cur]) + c * 64 +
          ((slot ^ ((c >> 1) & 3)) << 4));
    }
#pragma unroll
    for (int i = 0; i < 4; ++i)
#pragma unroll
      for (int j = 0; j < 4; ++j)
        acc[i][j] =
            __builtin_amdgcn_mfma_f32_16x16x32_bf16(af[i], bb[j], acc[i][j], 0, 0, 0);
    __syncthreads();
  }

  const long row0 = (long)mb * 128 + wr * 64 + ((lane >> 4) << 2);
  const int col0 = nb * 128 + wc * 64 + (lane & 15);
  if (mb >= mbT) {
    const long r0 = row0 - (long)mbT * 128;
#pragma unroll
    for (int i = 0; i < 4; ++i)
#pragma unroll
      for (int j = 0; j < 4; ++j)
#pragma unroll
        for (int r = 0; r < 4; ++r)
          Ct[(long)(col0 + j * 16) * ldct + (r0 + i * 16 + r)] = (CT)acc[i][j][r];
  } else {
#pragma unroll
    for (int i = 0; i < 4; ++i)
#pragma unroll
      for (int r = 0; r < 4; ++r)
#pragma unroll
        for (int j = 0; j < 4; ++j)
          C[(row0 + i * 16 + r) * ldc + (col0 + j * 16)] = (CT)acc[i][j][r];
  }
}

// ------------------------------------------- 256x256 8-phase GEMM (m201-style)
#define BARR __builtin_amdgcn_s_barrier()
#define SB0 __builtin_amdgcn_sched_barrier(0)
#define LGKM0                                             \
  asm volatile("s_waitcnt lgkmcnt(0)" ::: "memory");      \
  __builtin_amdgcn_sched_barrier(0)
#define VMC4 asm volatile("s_waitcnt vmcnt(4)" ::: "memory")

#define RDA(buf, ih)                                        \
  _Pragma("unroll") for (int i_ = 0; i_ < 4; ++i_)          \
  _Pragma("unroll") for (int k_ = 0; k_ < 2; ++k_)          \
      af[i_][k_] = ldaf(buf, (ih) * 4 + i_, k_)

#define RDB(buf, nh, dst)                                   \
  _Pragma("unroll") for (int n_ = 0; n_ < 2; ++n_)          \
  _Pragma("unroll") for (int k_ = 0; k_ < 2; ++k_)          \
      dst[n_][k_] = ldbf(buf, (nh) * 2 + n_, k_)

#define MM(ih, nh, B)                                                         \
  __builtin_amdgcn_s_setprio(1);                                              \
  _Pragma("unroll") for (int k_ = 0; k_ < 2; ++k_)                            \
  _Pragma("unroll") for (int i_ = 0; i_ < 4; ++i_)                            \
  _Pragma("unroll") for (int n_ = 0; n_ < 2; ++n_)                            \
      acc[(ih) * 4 + i_][(nh) * 2 + n_] =                                     \
          __builtin_amdgcn_mfma_f32_16x16x32_bf16(                            \
              af[i_][k_], B[n_][k_], acc[(ih) * 4 + i_][(nh) * 2 + n_], 0, 0, \
              0);                                                             \
  __builtin_amdgcn_s_setprio(0)

template <typename CT>
__global__ __launch_bounds__(512, 2) void k_gemm256(
    const bf16* __restrict__ A, const bf16* __restrict__ Bt, CT* __restrict__ C,
    int NT) {
  const int b0 = blockIdx.x;
  const int swz = (b0 & 7) * 32 + (b0 >> 3);
  const int mb = swz >> 2, nb = swz & 3;

  const int tid = threadIdx.x, lane = tid & 63, wid = tid >> 6;
  const int wr = wid >> 2, wc = wid & 3;
  const int x = lane & 15, g = lane >> 4;
  __shared__ bf16 Asl[2][16384];
  __shared__ bf16 Bsl[2][16384];

  const bf16* Ab = A + (long)mb * 256 * 1024;
  const bf16* Bb = Bt + (long)nb * 256 * 1024;
  const int srow8 = lane >> 3;
  const int skk = (((lane & 7) ^ srow8) << 3);

  auto stage = [&](int buf, int T, int j) {
    const bf16* src = (j < 2) ? Ab : Bb;
    bf16* db = ((j < 2) ? Asl[buf] : Bsl[buf]) + (j & 1) * 8192;
    const long ko = (long)T * 64 + skk;
#pragma unroll
    for (int i2 = 0; i2 < 2; ++i2) {
      const int c = wid * 2 + i2;
      GLL(src + (long)((j & 1) * 128 + c * 8 + srow8) * 1024 + ko, db + c * 512);
    }
  };
  auto ldaf = [&](int buf, int i, int s) {
    const int r = wr * 128 + i * 16 + x;
    return *reinterpret_cast<const bf16x8*>(
        reinterpret_cast<const char*>(Asl[buf]) + r * 128 +
        ((((s << 2) | g) ^ (r & 7)) << 4));
  };
  auto ldbf = [&](int buf, int n, int s) {
    const int c = wc * 64 + n * 16 + x;
    return *reinterpret_cast<const bf16x8*>(
        reinterpret_cast<const char*>(Bsl[buf]) + c * 128 +
        ((((s << 2) | g) ^ (c & 7)) << 4));
  };

  f32x4 acc[8][4] = {};
  bf16x8 af[4][2], bn01[2][2], bn23[2][2];

  stage(0, 0, 0); stage(0, 0, 1); stage(0, 0, 2); stage(0, 0, 3);
  stage(1, 1, 2); stage(1, 1, 3);
  VMC4;

  const int nit = NT >> 1;
  for (int it = 0; it < nit; ++it) {
    const int T = 2 * it;
    const int Tp1 = T + 1, Tp2 = (T + 2) % NT, Tp3 = (T + 3) % NT;
    // ph1 (publish T -> buf0)
    BARR; SB0;
    RDA(0, 0); RDB(0, 0, bn01);
    LGKM0;
    MM(0, 0, bn01);
    RDB(0, 1, bn23); stage(1, Tp1, 0);
    // ph2
    BARR; SB0; LGKM0;
    MM(0, 1, bn23);
    RDA(0, 1); stage(1, Tp1, 1);
    // ph3
    BARR; SB0; LGKM0;
    MM(1, 0, bn01);
    stage(0, Tp2, 2);
    // ph4
    BARR; SB0; LGKM0;
    MM(1, 1, bn23);
    stage(0, Tp2, 3);
    VMC4;
    // ph5 (publish T+1 -> buf1)
    BARR; SB0;
    RDA(1, 0); RDB(1, 0, bn01);
    LGKM0;
    MM(0, 0, bn01);
    RDB(1, 1, bn23); stage(0, Tp2, 0);
    // ph6
    BARR; SB0; LGKM0;
    MM(0, 1, bn23);
    RDA(1, 1); stage(0, Tp2, 1);
    // ph7
    BARR; SB0; LGKM0;
    MM(1, 0, bn01);
    stage(1, Tp3, 2);
    // ph8
    BARR; SB0; LGKM0;
    MM(1, 1, bn23);
    stage(1, Tp3, 3);
    VMC4;
  }

  const long row0 = (long)mb * 256 + wr * 128 + (g << 2);
  const int col0 = nb * 256 + wc * 64 + x;
#pragma unroll
  for (int i = 0; i < 8; ++i)
#pragma unroll
    for (int r = 0; r < 4; ++r)
#pragma unroll
      for (int n = 0; n < 4; ++n)
        C[(row0 + i * 16 + r) * 1024 + (col0 + n * 16)] = (CT)acc[i][n][r];
}

// ---------------------------------------------- split-K partial reduce (4 -> 1)
__global__ __launch_bounds__(256) void k_red4(const float* __restrict__ p,
                                              bf16* __restrict__ out) {
  const int i = blockIdx.x * 256 + threadIdx.x;
  const int SL = 512 * 1024;
  const int b = (i * 4) / SL;
  const int e = (i * 4) % SL;
  const float* base = p + (size_t)b * 4 * SL + e;
  float4 s0 = *reinterpret_cast<const float4*>(base);
  float4 s1 = *reinterpret_cast<const float4*>(base + SL);
  float4 s2 = *reinterpret_cast<const float4*>(base + 2 * SL);
  float4 s3 = *reinterpret_cast<const float4*>(base + 3 * SL);
  bf16x4 o;
  o[0] = (bf16)(s0.x + s1.x + s2.x + s3.x);
  o[1] = (bf16)(s0.y + s1.y + s2.y + s3.y);
  o[2] = (bf16)(s0.z + s1.z + s2.z + s3.z);
  o[3] = (bf16)(s0.w + s1.w + s2.w + s3.w);
  *reinterpret_cast<bf16x4*>(out + (size_t)b * SL + e) = o;
}

// ------------------------------------------------------------- fused attention
// grid (32 lt2, 16 h, 4 b), 512 thr = 8 waves / 128 q-rows per block.
__global__ __launch_bounds__(512) void k_attn(const bf16* __restrict__ q,
                                              const bf16* __restrict__ kc,
                                              const bf16* __restrict__ vT,
                                              bf16* __restrict__ aout) {
  const int lt = blockIdx.x, h = blockIdx.y, b = blockIdx.z;
  const int tid = threadIdx.x, lane = tid & 63, wid = tid >> 6;
  const int x = lane & 15, g = lane >> 4;
  __shared__ bf16 smem[32768];  // 64 KB
  bf16* Ks = smem;
  bf16* Vs = smem + 16384;

  const bf16* kb = kc + ((long)b * 256) * 1024 + h * 64;
#pragma unroll
  for (int it = 0; it < 4; ++it) {
    const int lin = it * 512 + tid;
    const int k = lin >> 3, s = lin & 7;
    const int rel = k & 31;
    const int pk = (k & ~31) | ((rel & 1) << 4) | ((rel >> 3) << 2) | ((rel >> 1) & 3);
    bf16x8 v = *reinterpret_cast<const bf16x8*>(kb + (long)k * 1024 + s * 8);
    *reinterpret_cast<bf16x8*>(reinterpret_cast<char*>(Ks) + pk * 128 +
                               ((s ^ (pk & 7)) << 4)) = v;
  }
  const bf16* vb = vT + (long)b * 1024 * 256 + (long)h * 64 * 256;
#pragma unroll
  for (int it = 0; it < 4; ++it) {
    const int lin = it * 512 + tid;
    const int d = lin >> 5, s = lin & 31;
    bf16x8 v = *reinterpret_cast<const bf16x8*>(vb + (long)d * 256 + s * 8);
    *reinterpret_cast<bf16x8*>(reinterpret_cast<char*>(Vs) + d * 512 +
                               ((s ^ (d & 7)) << 4)) = v;
  }

  const long qrow0 = (long)b * 4096 + lt * 128 + wid * 16;
  const bf16* qb = q + (qrow0 + x) * 1024 + h * 64;
  bf16x8 qf[2];
#pragma unroll
  for (int ks2 = 0; ks2 < 2; ++ks2)
    qf[ks2] = *reinterpret_cast<const bf16x8*>(qb + ks2 * 32 + g * 8);

  __syncthreads();

  f32x4 ln[16] = {};
  __builtin_amdgcn_s_setprio(1);
#pragma unroll
  for (int ks2 = 0; ks2 < 2; ++ks2) {
    const int slot = ks2 * 4 + g;
#pragma unroll
    for (int f = 0; f < 16; ++f) {
      const int row = f * 16 + x;
      bf16x8 kf = *reinterpret_cast<const bf16x8*>(
          reinterpret_cast<const char*>(Ks) + row * 128 + ((slot ^ (row & 7)) << 4));
      ln[f] = __builtin_amdgcn_mfma_f32_16x16x32_bf16(kf, qf[ks2], ln[f], 0, 0, 0);
    }
  }
  __builtin_amdgcn_s_setprio(0);

  float m = -1e30f;
#pragma unroll
  for (int f = 0; f < 16; ++f)
#pragma unroll
    for (int r = 0; r < 4; ++r) m = fmaxf(m, ln[f][r]);
  m = fmaxf(m, __shfl_xor(m, 16, 64));
  m = fmaxf(m, __shfl_xor(m, 32, 64));
  float sum = 0.f;
#pragma unroll
  for (int f = 0; f < 16; ++f)
#pragma unroll
    for (int r = 0; r < 4; ++r) {
      const float p = __expf((ln[f][r] - m) * 0.125f);
      ln[f][r] = p;
      sum += p;
    }
  sum += __shfl_xor(sum, 16, 64);
  sum += __shfl_xor(sum, 32, 64);
  const float inv = 1.f / sum;

  f32x4 oacc[4] = {};
  __builtin_amdgcn_s_setprio(1);
#pragma unroll
  for (int ks = 0; ks < 8; ++ks) {
    bf16x8 pa;
#pragma unroll
    for (int t = 0; t < 4; ++t) {
      pa[2 * t] = (bf16)ln[2 * ks][t];
      pa[2 * t + 1] = (bf16)ln[2 * ks + 1][t];
    }
    const int slot = ks * 4 + g;
#pragma unroll
    for (int nf = 0; nf < 4; ++nf) {
      const int d2 = nf * 16 + x;
      bf16x8 vv = *reinterpret_cast<const bf16x8*>(
          reinterpret_cast<const char*>(Vs) + d2 * 512 + ((slot ^ (d2 & 7)) << 4));
      oacc[nf] = __builtin_amdgcn_mfma_f32_16x16x32_bf16(pa, vv, oacc[nf], 0, 0, 0);
    }
  }
  __builtin_amdgcn_s_setprio(0);

  float invr[4];
#pragma unroll
  for (int r = 0; r < 4; ++r) invr[r] = __shfl(inv, 4 * g + r, 64);
  bf16* ob = aout + (qrow0 + 4 * g) * 1024 + h * 64 + x;
#pragma unroll
  for (int nf = 0; nf < 4; ++nf)
#pragma unroll
    for (int r = 0; r < 4; ++r)
      ob[(long)r * 1024 + nf * 16] = (bf16)(oacc[nf][r] * invr[r]);
}

// --------------------------------------------------------------------- launch
extern "C" void kernel_launch(void* const* d_in, const int* in_sizes, int n_in,
                              void* d_out, int out_size, void* d_ws, size_t ws_size,
                              hipStream_t stream) {
  const float* x  = (const float*)d_in[0];
  const float* Wq = (const float*)d_in[1];
  const float* Wk = (const float*)d_in[2];
  const float* Wv = (const float*)d_in[3];
  const float* Wo = (const float*)d_in[4];
  const float* Pk = (const float*)d_in[5];
  const float* Pv = (const float*)d_in[6];
  char* ws = (char*)d_ws;
  const long MB = 1024L * 1024;
  bf16* xbf = (bf16*)ws;
  bf16* XT  = (bf16*)(ws + 32 * MB);
  bf16* WqT = (bf16*)(ws + 64 * MB);
  bf16* WkT = (bf16*)(ws + 66 * MB);
  bf16* WvT = (bf16*)(ws + 68 * MB);
  bf16* WoT = (bf16*)(ws + 70 * MB);
  bf16* PT  = (bf16*)(ws + 72 * MB);
  float* XCp = (float*)(ws + 76 * MB);
  bf16* qbf = (bf16*)(ws + 76 * MB);
  bf16* XC  = (bf16*)(ws + 108 * MB);
  bf16* kcb = (bf16*)(ws + 112 * MB);
  bf16* vcT = (bf16*)(ws + 114 * MB);
  bf16* aout = xbf;
  const int BIG = 1 << 30;
  (void)in_sizes; (void)n_in; (void)out_size; (void)ws_size;

  // 1) all casts/transposes, exact flat grid (5632 blocks)
  XP xp;
  for (int b = 0; b < 4; ++b) {
    xp.src[b] = x + (long)b * 4096 * 1024;
    xp.dst[b] = xbf + (long)b * 4096 * 1024;
    xp.dstT[b] = XT + (long)b * 1024 * 4096;
    xp.R[b] = 4096; xp.C[b] = 1024;
  }
  const float* wsrc[4] = {Wq, Wk, Wv, Wo};
  bf16* wdst[4] = {WqT, WkT, WvT, WoT};
  for (int i = 0; i < 4; ++i) {
    xp.src[4 + i] = wsrc[i];
    xp.dst[4 + i] = nullptr;
    xp.dstT[4 + i] = wdst[i];
    xp.R[4 + i] = 1024; xp.C[4 + i] = 1024;
  }
  xp.src[8] = Pk; xp.dst[8] = nullptr; xp.dstT[8] = PT;
  xp.R[8] = 4096; xp.C[8] = 256;
  xp.src[9] = Pv; xp.dst[9] = nullptr; xp.dstT[9] = PT + 256 * 4096;
  xp.R[9] = 4096; xp.C[9] = 256;
  k_xpose<<<dim3(5632), 256, 0, stream>>>(xp);

  // 2) XC split-K x4 partials + reduce
  k_gemm_nt<float><<<dim3(4, 8, 16), 256, 0, stream>>>(
      PT, XT, XT, XCp, 4096, 4096, 1024, 1024, 0, 1024L * 4096, 512L * 1024, 4, 1024,
      BIG, XCp, 0, 1024, BIG);
  k_red4<<<dim3(2048), 256, 0, stream>>>(XCp, XC);

  // 3) kc = XCk@Wk ; vcT = (XCv@Wv)^T
  k_gemm_nt<bf16><<<dim3(4, 8, 4), 256, 0, stream>>>(
      XC, WkT, WvT, kcb, 1024, 1024, 1024, 1024, 512L * 1024, 0, 256L * 1024, 1, 0, 2,
      vcT, 1024L * 256, 256, 2);

  // 4) Q = x @ Wq   (8-phase 256^2 kernel, NT = 16)
  k_gemm256<bf16><<<dim3(256), 512, 0, stream>>>(xbf, WqT, qbf, 16);

  // 5) attention
  k_attn<<<dim3(32, 16, 4), 512, 0, stream>>>(qbf, kcb, vcT, aout);

  // 6) out = aout @ Wo (fp32 out)
  k_gemm256<float><<<dim3(256), 512, 0, stream>>>(aout, WoT, (float*)d_out, 16);
}

// Round 21
// 188.726 us; speedup vs baseline: 1.0278x; 1.0088x over previous
//
#include <hip/hip_runtime.h>
#include <stdint.h>

typedef __bf16 bf16;
typedef __bf16 bf16x4 __attribute__((ext_vector_type(4)));
typedef __bf16 bf16x8 __attribute__((ext_vector_type(8)));
typedef float f32x4 __attribute__((ext_vector_type(4)));

// ------------------------------------- unified cast / transpose-cast kernel
// (R17-proven best: single 64x64 tile, [64][65] f32 LDS, 2-way-max banking)
struct XP {
  const float* src[10];
  bf16* dst[10];
  bf16* dstT[10];
  int R[10], C[10];
};

__global__ __launch_bounds__(256) void k_xpose(XP a) {
  const int bid = blockIdx.x;
  int z, bx, by;
  if (bid < 4096) {
    z = bid >> 10; int r = bid & 1023; by = r >> 4; bx = r & 15;
  } else if (bid < 5120) {
    int r = bid - 4096; z = 4 + (r >> 8); r &= 255; by = r >> 4; bx = r & 15;
  } else {
    int r = bid - 5120; z = 8 + (r >> 8); r &= 255; by = r >> 2; bx = r & 3;
  }
  const int R = a.R[z], C = a.C[z];
  const float* __restrict__ src = a.src[z];
  bf16* __restrict__ dst = a.dst[z];
  bf16* __restrict__ dstT = a.dstT[z];
  const int r0 = by * 64, c0 = bx * 64;
  __shared__ float tile[64][65];
  const int t = threadIdx.x;

  const int rr = t >> 3, c8 = (t & 7) * 8;
#pragma unroll
  for (int i = 0; i < 2; ++i) {
    const int r = i * 32 + rr;
    const float* sp = &src[(size_t)(r0 + r) * C + c0 + c8];
    float4 v0 = *reinterpret_cast<const float4*>(sp);
    float4 v1 = *reinterpret_cast<const float4*>(sp + 4);
    tile[r][c8] = v0.x; tile[r][c8 + 1] = v0.y;
    tile[r][c8 + 2] = v0.z; tile[r][c8 + 3] = v0.w;
    tile[r][c8 + 4] = v1.x; tile[r][c8 + 5] = v1.y;
    tile[r][c8 + 6] = v1.z; tile[r][c8 + 7] = v1.w;
    if (dst) {
      bf16x8 o;
      o[0] = (bf16)v0.x; o[1] = (bf16)v0.y; o[2] = (bf16)v0.z; o[3] = (bf16)v0.w;
      o[4] = (bf16)v1.x; o[5] = (bf16)v1.y; o[6] = (bf16)v1.z; o[7] = (bf16)v1.w;
      *reinterpret_cast<bf16x8*>(&dst[(size_t)(r0 + r) * C + c0 + c8]) = o;
    }
  }
  __syncthreads();

#pragma unroll
  for (int h = 0; h < 2; ++h) {
    const int q = h * 256 + t;
    const int c = q >> 3, u = (q & 7) * 8;
    bf16x8 o;
#pragma unroll
    for (int j = 0; j < 8; ++j) o[j] = (bf16)tile[u + j][c];
    *reinterpret_cast<bf16x8*>(&dstT[(size_t)(c0 + c) * R + r0 + u]) = o;
  }
}

#define GLL(gp, lp)                                              \
  __builtin_amdgcn_global_load_lds(                              \
      (const __attribute__((address_space(1))) void*)(gp),       \
      (__attribute__((address_space(3))) void*)(lp), 16, 0, 0)

// ---------------------------------------------------------------- NT bf16 GEMM
template <typename CT>
__global__ __launch_bounds__(256) void k_gemm_nt(
    const bf16* __restrict__ A, const bf16* __restrict__ Bt,
    const bf16* __restrict__ Bt2, CT* __restrict__ C,
    int lda, int ldb, int ldc, int Kd, long sA, long sB, long sC,
    int zmod, long kOff, int mbSplit, CT* __restrict__ Ct, long sCt, int ldct,
    int mbT) {
  int zb = blockIdx.z, kc = 0;
  if (zmod > 1) { zb = blockIdx.z / zmod; kc = blockIdx.z % zmod; }
  const int mb = blockIdx.x, nb = blockIdx.y;
  A += (long)zb * sA + (long)kc * kOff;
  const bf16* Bsel = (mb < mbSplit) ? Bt : Bt2;
  Bsel += (long)zb * sB + (long)kc * kOff;
  C += (long)blockIdx.z * sC;
  Ct += (long)blockIdx.z * sCt;

  __shared__ bf16 As[2][128 * 32];
  __shared__ bf16 Bs[2][128 * 32];
  const int tid = threadIdx.x, lane = tid & 63, wid = tid >> 6;
  const int wr = wid >> 1, wc = wid & 1;
  const int srow = lane >> 2;
  const int skk = (((lane & 3) ^ ((srow >> 1) & 3)) << 3);

  f32x4 acc[4][4] = {};
  const bf16* Abase = A + (long)mb * 128 * lda;
  const bf16* Bbase = Bsel + (long)nb * 128 * ldb;

  auto stage = [&](int buf, int k0) {
#pragma unroll
    for (int i = 0; i < 2; ++i) {
      const int ch = wid * 2 + i;
      const int row = ch * 16 + srow;
      GLL(Abase + (long)row * lda + k0 + skk, &As[buf][ch * 512]);
      GLL(Bbase + (long)row * ldb + k0 + skk, &Bs[buf][ch * 512]);
    }
  };

  stage(0, 0);
  const int nk = Kd >> 5;
  for (int kt = 0; kt < nk; ++kt) {
    const int cur = kt & 1;
    if (kt + 1 < nk) stage(cur ^ 1, (kt + 1) << 5);
    __syncthreads();
    const int slot = lane >> 4;
    bf16x8 af[4], bb[4];
#pragma unroll
    for (int i = 0; i < 4; ++i) {
      const int r = wr * 64 + i * 16 + (lane & 15);
      af[i] = *reinterpret_cast<const bf16x8*>(
          reinterpret_cast<const char*>(As[cur]) + r * 64 +
          ((slot ^ ((r >> 1) & 3)) << 4));
      const int c = wc * 64 + i * 16 + (lane & 15);
      bb[i] = *reinterpret_cast<const bf16x8*>(
          reinterpret_cast<const char*>(Bs[cur]) + c * 64 +
          ((slot ^ ((c >> 1) & 3)) << 4));
    }
#pragma unroll
    for (int i = 0; i < 4; ++i)
#pragma unroll
      for (int j = 0; j < 4; ++j)
        acc[i][j] =
            __builtin_amdgcn_mfma_f32_16x16x32_bf16(af[i], bb[j], acc[i][j], 0, 0, 0);
    __syncthreads();
  }

  const long row0 = (long)mb * 128 + wr * 64 + ((lane >> 4) << 2);
  const int col0 = nb * 128 + wc * 64 + (lane & 15);
  if (mb >= mbT) {
    const long r0 = row0 - (long)mbT * 128;
#pragma unroll
    for (int i = 0; i < 4; ++i)
#pragma unroll
      for (int j = 0; j < 4; ++j)
#pragma unroll
        for (int r = 0; r < 4; ++r)
          Ct[(long)(col0 + j * 16) * ldct + (r0 + i * 16 + r)] = (CT)acc[i][j][r];
  } else {
#pragma unroll
    for (int i = 0; i < 4; ++i)
#pragma unroll
      for (int r = 0; r < 4; ++r)
#pragma unroll
        for (int j = 0; j < 4; ++j)
          C[(row0 + i * 16 + r) * ldc + (col0 + j * 16)] = (CT)acc[i][j][r];
  }
}

// ------------------------------------------- 256x256 8-phase GEMM (m201-style)
#define BARR __builtin_amdgcn_s_barrier()
#define SB0 __builtin_amdgcn_sched_barrier(0)
#define LGKM0                                             \
  asm volatile("s_waitcnt lgkmcnt(0)" ::: "memory");      \
  __builtin_amdgcn_sched_barrier(0)
#define VMC4 asm volatile("s_waitcnt vmcnt(4)" ::: "memory")

#define RDA(buf, ih)                                        \
  _Pragma("unroll") for (int i_ = 0; i_ < 4; ++i_)          \
  _Pragma("unroll") for (int k_ = 0; k_ < 2; ++k_)          \
      af[i_][k_] = ldaf(buf, (ih) * 4 + i_, k_)

#define RDB(buf, nh, dst)                                   \
  _Pragma("unroll") for (int n_ = 0; n_ < 2; ++n_)          \
  _Pragma("unroll") for (int k_ = 0; k_ < 2; ++k_)          \
      dst[n_][k_] = ldbf(buf, (nh) * 2 + n_, k_)

#define MM(ih, nh, B)                                                         \
  __builtin_amdgcn_s_setprio(1);                                              \
  _Pragma("unroll") for (int k_ = 0; k_ < 2; ++k_)                            \
  _Pragma("unroll") for (int i_ = 0; i_ < 4; ++i_)                            \
  _Pragma("unroll") for (int n_ = 0; n_ < 2; ++n_)                            \
      acc[(ih) * 4 + i_][(nh) * 2 + n_] =                                     \
          __builtin_amdgcn_mfma_f32_16x16x32_bf16(                            \
              af[i_][k_], B[n_][k_], acc[(ih) * 4 + i_][(nh) * 2 + n_], 0, 0, \
              0);                                                             \
  __builtin_amdgcn_s_setprio(0)

template <typename CT>
__global__ __launch_bounds__(512, 2) void k_gemm256(
    const bf16* __restrict__ A, const bf16* __restrict__ Bt, CT* __restrict__ C,
    int NT) {
  const int b0 = blockIdx.x;
  const int swz = (b0 & 7) * 32 + (b0 >> 3);
  const int mb = swz >> 2, nb = swz & 3;

  const int tid = threadIdx.x, lane = tid & 63, wid = tid >> 6;
  const int wr = wid >> 2, wc = wid & 3;
  const int x = lane & 15, g = lane >> 4;
  __shared__ bf16 Asl[2][16384];
  __shared__ bf16 Bsl[2][16384];

  const bf16* Ab = A + (long)mb * 256 * 1024;
  const bf16* Bb = Bt + (long)nb * 256 * 1024;
  const int srow8 = lane >> 3;
  const int skk = (((lane & 7) ^ srow8) << 3);

  auto stage = [&](int buf, int T, int j) {
    const bf16* src = (j < 2) ? Ab : Bb;
    bf16* db = ((j < 2) ? Asl[buf] : Bsl[buf]) + (j & 1) * 8192;
    const long ko = (long)T * 64 + skk;
#pragma unroll
    for (int i2 = 0; i2 < 2; ++i2) {
      const int c = wid * 2 + i2;
      GLL(src + (long)((j & 1) * 128 + c * 8 + srow8) * 1024 + ko, db + c * 512);
    }
  };
  auto ldaf = [&](int buf, int i, int s) {
    const int r = wr * 128 + i * 16 + x;
    return *reinterpret_cast<const bf16x8*>(
        reinterpret_cast<const char*>(Asl[buf]) + r * 128 +
        ((((s << 2) | g) ^ (r & 7)) << 4));
  };
  auto ldbf = [&](int buf, int n, int s) {
    const int c = wc * 64 + n * 16 + x;
    return *reinterpret_cast<const bf16x8*>(
        reinterpret_cast<const char*>(Bsl[buf]) + c * 128 +
        ((((s << 2) | g) ^ (c & 7)) << 4));
  };

  f32x4 acc[8][4] = {};
  bf16x8 af[4][2], bn01[2][2], bn23[2][2];

  stage(0, 0, 0); stage(0, 0, 1); stage(0, 0, 2); stage(0, 0, 3);
  stage(1, 1, 2); stage(1, 1, 3);
  VMC4;

  const int nit = NT >> 1;
  for (int it = 0; it < nit; ++it) {
    const int T = 2 * it;
    const int Tp1 = T + 1, Tp2 = (T + 2) % NT, Tp3 = (T + 3) % NT;
    // ph1 (publish T -> buf0)
    BARR; SB0;
    RDA(0, 0); RDB(0, 0, bn01);
    LGKM0;
    MM(0, 0, bn01);
    RDB(0, 1, bn23); stage(1, Tp1, 0);
    // ph2
    BARR; SB0; LGKM0;
    MM(0, 1, bn23);
    RDA(0, 1); stage(1, Tp1, 1);
    // ph3
    BARR; SB0; LGKM0;
    MM(1, 0, bn01);
    stage(0, Tp2, 2);
    // ph4
    BARR; SB0; LGKM0;
    MM(1, 1, bn23);
    stage(0, Tp2, 3);
    VMC4;
    // ph5 (publish T+1 -> buf1)
    BARR; SB0;
    RDA(1, 0); RDB(1, 0, bn01);
    LGKM0;
    MM(0, 0, bn01);
    RDB(1, 1, bn23); stage(0, Tp2, 0);
    // ph6
    BARR; SB0; LGKM0;
    MM(0, 1, bn23);
    RDA(1, 1); stage(0, Tp2, 1);
    // ph7
    BARR; SB0; LGKM0;
    MM(1, 0, bn01);
    stage(1, Tp3, 2);
    // ph8
    BARR; SB0; LGKM0;
    MM(1, 1, bn23);
    stage(1, Tp3, 3);
    VMC4;
  }

  const long row0 = (long)mb * 256 + wr * 128 + (g << 2);
  const int col0 = nb * 256 + wc * 64 + x;
#pragma unroll
  for (int i = 0; i < 8; ++i)
#pragma unroll
    for (int r = 0; r < 4; ++r)
#pragma unroll
      for (int n = 0; n < 4; ++n)
        C[(row0 + i * 16 + r) * 1024 + (col0 + n * 16)] = (CT)acc[i][n][r];
}

// ------------------------------------ split-K partial reduce (4 bf16 -> 1 bf16)
__global__ __launch_bounds__(256) void k_red4b(const bf16* __restrict__ p,
                                               bf16* __restrict__ out) {
  const int i = blockIdx.x * 256 + threadIdx.x;
  const int SL = 512 * 1024;
  const int b = (i * 4) / SL;
  const int e = (i * 4) % SL;
  const bf16* base = p + (size_t)b * 4 * SL + e;
  bf16x4 s0 = *reinterpret_cast<const bf16x4*>(base);
  bf16x4 s1 = *reinterpret_cast<const bf16x4*>(base + SL);
  bf16x4 s2 = *reinterpret_cast<const bf16x4*>(base + 2 * SL);
  bf16x4 s3 = *reinterpret_cast<const bf16x4*>(base + 3 * SL);
  bf16x4 o;
#pragma unroll
  for (int j = 0; j < 4; ++j)
    o[j] = (bf16)((float)s0[j] + (float)s1[j] + (float)s2[j] + (float)s3[j]);
  *reinterpret_cast<bf16x4*>(out + (size_t)b * SL + e) = o;
}

// ------------------------------------------------------------- fused attention
// grid (32 lt2, 16 h, 4 b), 512 thr = 8 waves / 128 q-rows per block.
__global__ __launch_bounds__(512) void k_attn(const bf16* __restrict__ q,
                                              const bf16* __restrict__ kc,
                                              const bf16* __restrict__ vT,
                                              bf16* __restrict__ aout) {
  const int lt = blockIdx.x, h = blockIdx.y, b = blockIdx.z;
  const int tid = threadIdx.x, lane = tid & 63, wid = tid >> 6;
  const int x = lane & 15, g = lane >> 4;
  __shared__ bf16 smem[32768];  // 64 KB
  bf16* Ks = smem;
  bf16* Vs = smem + 16384;

  const bf16* kb = kc + ((long)b * 256) * 1024 + h * 64;
#pragma unroll
  for (int it = 0; it < 4; ++it) {
    const int lin = it * 512 + tid;
    const int k = lin >> 3, s = lin & 7;
    const int rel = k & 31;
    const int pk = (k & ~31) | ((rel & 1) << 4) | ((rel >> 3) << 2) | ((rel >> 1) & 3);
    bf16x8 v = *reinterpret_cast<const bf16x8*>(kb + (long)k * 1024 + s * 8);
    *reinterpret_cast<bf16x8*>(reinterpret_cast<char*>(Ks) + pk * 128 +
                               ((s ^ (pk & 7)) << 4)) = v;
  }
  const bf16* vb = vT + (long)b * 1024 * 256 + (long)h * 64 * 256;
#pragma unroll
  for (int it = 0; it < 4; ++it) {
    const int lin = it * 512 + tid;
    const int d = lin >> 5, s = lin & 31;
    bf16x8 v = *reinterpret_cast<const bf16x8*>(vb + (long)d * 256 + s * 8);
    *reinterpret_cast<bf16x8*>(reinterpret_cast<char*>(Vs) + d * 512 +
                               ((s ^ (d & 7)) << 4)) = v;
  }

  const long qrow0 = (long)b * 4096 + lt * 128 + wid * 16;
  const bf16* qb = q + (qrow0 + x) * 1024 + h * 64;
  bf16x8 qf[2];
#pragma unroll
  for (int ks2 = 0; ks2 < 2; ++ks2)
    qf[ks2] = *reinterpret_cast<const bf16x8*>(qb + ks2 * 32 + g * 8);

  __syncthreads();

  f32x4 ln[16] = {};
  __builtin_amdgcn_s_setprio(1);
#pragma unroll
  for (int ks2 = 0; ks2 < 2; ++ks2) {
    const int slot = ks2 * 4 + g;
#pragma unroll
    for (int f = 0; f < 16; ++f) {
      const int row = f * 16 + x;
      bf16x8 kf = *reinterpret_cast<const bf16x8*>(
          reinterpret_cast<const char*>(Ks) + row * 128 + ((slot ^ (row & 7)) << 4));
      ln[f] = __builtin_amdgcn_mfma_f32_16x16x32_bf16(kf, qf[ks2], ln[f], 0, 0, 0);
    }
  }
  __builtin_amdgcn_s_setprio(0);

  float m = -1e30f;
#pragma unroll
  for (int f = 0; f < 16; ++f)
#pragma unroll
    for (int r = 0; r < 4; ++r) m = fmaxf(m, ln[f][r]);
  m = fmaxf(m, __shfl_xor(m, 16, 64));
  m = fmaxf(m, __shfl_xor(m, 32, 64));
  float sum = 0.f;
#pragma unroll
  for (int f = 0; f < 16; ++f)
#pragma unroll
    for (int r = 0; r < 4; ++r) {
      const float p = __expf((ln[f][r] - m) * 0.125f);
      ln[f][r] = p;
      sum += p;
    }
  sum += __shfl_xor(sum, 16, 64);
  sum += __shfl_xor(sum, 32, 64);
  const float inv = 1.f / sum;

  f32x4 oacc[4] = {};
  __builtin_amdgcn_s_setprio(1);
#pragma unroll
  for (int ks = 0; ks < 8; ++ks) {
    bf16x8 pa;
#pragma unroll
    for (int t = 0; t < 4; ++t) {
      pa[2 * t] = (bf16)ln[2 * ks][t];
      pa[2 * t + 1] = (bf16)ln[2 * ks + 1][t];
    }
    const int slot = ks * 4 + g;
#pragma unroll
    for (int nf = 0; nf < 4; ++nf) {
      const int d2 = nf * 16 + x;
      bf16x8 vv = *reinterpret_cast<const bf16x8*>(
          reinterpret_cast<const char*>(Vs) + d2 * 512 + ((slot ^ (d2 & 7)) << 4));
      oacc[nf] = __builtin_amdgcn_mfma_f32_16x16x32_bf16(pa, vv, oacc[nf], 0, 0, 0);
    }
  }
  __builtin_amdgcn_s_setprio(0);

  float invr[4];
#pragma unroll
  for (int r = 0; r < 4; ++r) invr[r] = __shfl(inv, 4 * g + r, 64);
  bf16* ob = aout + (qrow0 + 4 * g) * 1024 + h * 64 + x;
#pragma unroll
  for (int nf = 0; nf < 4; ++nf)
#pragma unroll
    for (int r = 0; r < 4; ++r)
      ob[(long)r * 1024 + nf * 16] = (bf16)(oacc[nf][r] * invr[r]);
}

// --------------------------------------------------------------------- launch
extern "C" void kernel_launch(void* const* d_in, const int* in_sizes, int n_in,
                              void* d_out, int out_size, void* d_ws, size_t ws_size,
                              hipStream_t stream) {
  const float* x  = (const float*)d_in[0];
  const float* Wq = (const float*)d_in[1];
  const float* Wk = (const float*)d_in[2];
  const float* Wv = (const float*)d_in[3];
  const float* Wo = (const float*)d_in[4];
  const float* Pk = (const float*)d_in[5];
  const float* Pv = (const float*)d_in[6];
  char* ws = (char*)d_ws;
  const long MB = 1024L * 1024;
  bf16* xbf = (bf16*)ws;
  bf16* XT  = (bf16*)(ws + 32 * MB);
  bf16* WqT = (bf16*)(ws + 64 * MB);
  bf16* WkT = (bf16*)(ws + 66 * MB);
  bf16* WvT = (bf16*)(ws + 68 * MB);
  bf16* WoT = (bf16*)(ws + 70 * MB);
  bf16* PT  = (bf16*)(ws + 72 * MB);
  bf16* XCp = (bf16*)(ws + 76 * MB);   // 16 MB bf16 split-K partials (16 slabs)
  bf16* qbf = (bf16*)(ws + 76 * MB);   // 32 MB (after reduce; XCp dead)
  bf16* XC  = (bf16*)(ws + 108 * MB);
  bf16* kcb = (bf16*)(ws + 112 * MB);
  bf16* vcT = (bf16*)(ws + 114 * MB);
  bf16* aout = xbf;
  const int BIG = 1 << 30;
  (void)in_sizes; (void)n_in; (void)out_size; (void)ws_size;

  // 1) all casts/transposes, exact flat grid (5632 blocks)
  XP xp;
  for (int b = 0; b < 4; ++b) {
    xp.src[b] = x + (long)b * 4096 * 1024;
    xp.dst[b] = xbf + (long)b * 4096 * 1024;
    xp.dstT[b] = XT + (long)b * 1024 * 4096;
    xp.R[b] = 4096; xp.C[b] = 1024;
  }
  const float* wsrc[4] = {Wq, Wk, Wv, Wo};
  bf16* wdst[4] = {WqT, WkT, WvT, WoT};
  for (int i = 0; i < 4; ++i) {
    xp.src[4 + i] = wsrc[i];
    xp.dst[4 + i] = nullptr;
    xp.dstT[4 + i] = wdst[i];
    xp.R[4 + i] = 1024; xp.C[4 + i] = 1024;
  }
  xp.src[8] = Pk; xp.dst[8] = nullptr; xp.dstT[8] = PT;
  xp.R[8] = 4096; xp.C[8] = 256;
  xp.src[9] = Pv; xp.dst[9] = nullptr; xp.dstT[9] = PT + 256 * 4096;
  xp.R[9] = 4096; xp.C[9] = 256;
  k_xpose<<<dim3(5632), 256, 0, stream>>>(xp);

  // 2) XC split-K x4 partials (bf16) + reduce
  k_gemm_nt<bf16><<<dim3(4, 8, 16), 256, 0, stream>>>(
      PT, XT, XT, XCp, 4096, 4096, 1024, 1024, 0, 1024L * 4096, 512L * 1024, 4, 1024,
      BIG, XCp, 0, 1024, BIG);
  k_red4b<<<dim3(2048), 256, 0, stream>>>(XCp, XC);

  // 3) kc = XCk@Wk ; vcT = (XCv@Wv)^T
  k_gemm_nt<bf16><<<dim3(4, 8, 4), 256, 0, stream>>>(
      XC, WkT, WvT, kcb, 1024, 1024, 1024, 1024, 512L * 1024, 0, 256L * 1024, 1, 0, 2,
      vcT, 1024L * 256, 256, 2);

  // 4) Q = x @ Wq   (8-phase 256^2 kernel, NT = 16)
  k_gemm256<bf16><<<dim3(256), 512, 0, stream>>>(xbf, WqT, qbf, 16);

  // 5) attention
  k_attn<<<dim3(32, 16, 4), 512, 0, stream>>>(qbf, kcb, vcT, aout);

  // 6) out = aout @ Wo (fp32 out)
  k_gemm256<float><<<dim3(256), 512, 0, stream>>>(aout, WoT, (float*)d_out, 16);
}

// Round 22
// 188.723 us; speedup vs baseline: 1.0278x; 1.0000x over previous
//
#include <hip/hip_runtime.h>
#include <stdint.h>

typedef __bf16 bf16;
typedef __bf16 bf16x4 __attribute__((ext_vector_type(4)));
typedef __bf16 bf16x8 __attribute__((ext_vector_type(8)));
typedef float f32x4 __attribute__((ext_vector_type(4)));

// ------------------------------------- unified cast / transpose-cast kernel
// (R17-proven best: single 64x64 tile, [64][65] f32 LDS, 2-way-max banking)
struct XP {
  const float* src[10];
  bf16* dst[10];
  bf16* dstT[10];
  int R[10], C[10];
};

__global__ __launch_bounds__(256) void k_xpose(XP a) {
  const int bid = blockIdx.x;
  int z, bx, by;
  if (bid < 4096) {
    z = bid >> 10; int r = bid & 1023; by = r >> 4; bx = r & 15;
  } else if (bid < 5120) {
    int r = bid - 4096; z = 4 + (r >> 8); r &= 255; by = r >> 4; bx = r & 15;
  } else {
    int r = bid - 5120; z = 8 + (r >> 8); r &= 255; by = r >> 2; bx = r & 3;
  }
  const int R = a.R[z], C = a.C[z];
  const float* __restrict__ src = a.src[z];
  bf16* __restrict__ dst = a.dst[z];
  bf16* __restrict__ dstT = a.dstT[z];
  const int r0 = by * 64, c0 = bx * 64;
  __shared__ float tile[64][65];
  const int t = threadIdx.x;

  const int rr = t >> 3, c8 = (t & 7) * 8;
#pragma unroll
  for (int i = 0; i < 2; ++i) {
    const int r = i * 32 + rr;
    const float* sp = &src[(size_t)(r0 + r) * C + c0 + c8];
    float4 v0 = *reinterpret_cast<const float4*>(sp);
    float4 v1 = *reinterpret_cast<const float4*>(sp + 4);
    tile[r][c8] = v0.x; tile[r][c8 + 1] = v0.y;
    tile[r][c8 + 2] = v0.z; tile[r][c8 + 3] = v0.w;
    tile[r][c8 + 4] = v1.x; tile[r][c8 + 5] = v1.y;
    tile[r][c8 + 6] = v1.z; tile[r][c8 + 7] = v1.w;
    if (dst) {
      bf16x8 o;
      o[0] = (bf16)v0.x; o[1] = (bf16)v0.y; o[2] = (bf16)v0.z; o[3] = (bf16)v0.w;
      o[4] = (bf16)v1.x; o[5] = (bf16)v1.y; o[6] = (bf16)v1.z; o[7] = (bf16)v1.w;
      *reinterpret_cast<bf16x8*>(&dst[(size_t)(r0 + r) * C + c0 + c8]) = o;
    }
  }
  __syncthreads();

#pragma unroll
  for (int h = 0; h < 2; ++h) {
    const int q = h * 256 + t;
    const int c = q >> 3, u = (q & 7) * 8;
    bf16x8 o;
#pragma unroll
    for (int j = 0; j < 8; ++j) o[j] = (bf16)tile[u + j][c];
    *reinterpret_cast<bf16x8*>(&dstT[(size_t)(c0 + c) * R + r0 + u]) = o;
  }
}

#define GLL(gp, lp)                                              \
  __builtin_amdgcn_global_load_lds(                              \
      (const __attribute__((address_space(1))) void*)(gp),       \
      (__attribute__((address_space(3))) void*)(lp), 16, 0, 0)

// ---------------------------------------------------------------- NT bf16 GEMM
template <typename CT>
__global__ __launch_bounds__(256) void k_gemm_nt(
    const bf16* __restrict__ A, const bf16* __restrict__ Bt,
    const bf16* __restrict__ Bt2, CT* __restrict__ C,
    int lda, int ldb, int ldc, int Kd, long sA, long sB, long sC,
    int zmod, long kOff, int mbSplit, CT* __restrict__ Ct, long sCt, int ldct,
    int mbT) {
  int zb = blockIdx.z, kc = 0;
  if (zmod > 1) { zb = blockIdx.z / zmod; kc = blockIdx.z % zmod; }
  const int mb = blockIdx.x, nb = blockIdx.y;
  A += (long)zb * sA + (long)kc * kOff;
  const bf16* Bsel = (mb < mbSplit) ? Bt : Bt2;
  Bsel += (long)zb * sB + (long)kc * kOff;
  C += (long)blockIdx.z * sC;
  Ct += (long)blockIdx.z * sCt;

  __shared__ bf16 As[2][128 * 32];
  __shared__ bf16 Bs[2][128 * 32];
  const int tid = threadIdx.x, lane = tid & 63, wid = tid >> 6;
  const int wr = wid >> 1, wc = wid & 1;
  const int srow = lane >> 2;
  const int skk = (((lane & 3) ^ ((srow >> 1) & 3)) << 3);

  f32x4 acc[4][4] = {};
  const bf16* Abase = A + (long)mb * 128 * lda;
  const bf16* Bbase = Bsel + (long)nb * 128 * ldb;

  auto stage = [&](int buf, int k0) {
#pragma unroll
    for (int i = 0; i < 2; ++i) {
      const int ch = wid * 2 + i;
      const int row = ch * 16 + srow;
      GLL(Abase + (long)row * lda + k0 + skk, &As[buf][ch * 512]);
      GLL(Bbase + (long)row * ldb + k0 + skk, &Bs[buf][ch * 512]);
    }
  };

  stage(0, 0);
  const int nk = Kd >> 5;
  for (int kt = 0; kt < nk; ++kt) {
    const int cur = kt & 1;
    if (kt + 1 < nk) stage(cur ^ 1, (kt + 1) << 5);
    __syncthreads();
    const int slot = lane >> 4;
    bf16x8 af[4], bb[4];
#pragma unroll
    for (int i = 0; i < 4; ++i) {
      const int r = wr * 64 + i * 16 + (lane & 15);
      af[i] = *reinterpret_cast<const bf16x8*>(
          reinterpret_cast<const char*>(As[cur]) + r * 64 +
          ((slot ^ ((r >> 1) & 3)) << 4));
      const int c = wc * 64 + i * 16 + (lane & 15);
      bb[i] = *reinterpret_cast<const bf16x8*>(
          reinterpret_cast<const char*>(Bs[cur]) + c * 64 +
          ((slot ^ ((c >> 1) & 3)) << 4));
    }
#pragma unroll
    for (int i = 0; i < 4; ++i)
#pragma unroll
      for (int j = 0; j < 4; ++j)
        acc[i][j] =
            __builtin_amdgcn_mfma_f32_16x16x32_bf16(af[i], bb[j], acc[i][j], 0, 0, 0);
    __syncthreads();
  }

  const long row0 = (long)mb * 128 + wr * 64 + ((lane >> 4) << 2);
  const int col0 = nb * 128 + wc * 64 + (lane & 15);
  if (mb >= mbT) {
    const long r0 = row0 - (long)mbT * 128;
#pragma unroll
    for (int i = 0; i < 4; ++i)
#pragma unroll
      for (int j = 0; j < 4; ++j)
#pragma unroll
        for (int r = 0; r < 4; ++r)
          Ct[(long)(col0 + j * 16) * ldct + (r0 + i * 16 + r)] = (CT)acc[i][j][r];
  } else {
#pragma unroll
    for (int i = 0; i < 4; ++i)
#pragma unroll
      for (int r = 0; r < 4; ++r)
#pragma unroll
        for (int j = 0; j < 4; ++j)
          C[(row0 + i * 16 + r) * ldc + (col0 + j * 16)] = (CT)acc[i][j][r];
  }
}

// ------------------------------------------- 256x256 8-phase GEMM (m201-style)
#define BARR __builtin_amdgcn_s_barrier()
#define SB0 __builtin_amdgcn_sched_barrier(0)
#define LGKM0                                             \
  asm volatile("s_waitcnt lgkmcnt(0)" ::: "memory");      \
  __builtin_amdgcn_sched_barrier(0)
#define VMC4 asm volatile("s_waitcnt vmcnt(4)" ::: "memory")

#define RDA(buf, ih)                                        \
  _Pragma("unroll") for (int i_ = 0; i_ < 4; ++i_)          \
  _Pragma("unroll") for (int k_ = 0; k_ < 2; ++k_)          \
      af[i_][k_] = ldaf(buf, (ih) * 4 + i_, k_)

#define RDB(buf, nh, dst)                                   \
  _Pragma("unroll") for (int n_ = 0; n_ < 2; ++n_)          \
  _Pragma("unroll") for (int k_ = 0; k_ < 2; ++k_)          \
      dst[n_][k_] = ldbf(buf, (nh) * 2 + n_, k_)

#define MM(ih, nh, B)                                                         \
  __builtin_amdgcn_s_setprio(1);                                              \
  _Pragma("unroll") for (int k_ = 0; k_ < 2; ++k_)                            \
  _Pragma("unroll") for (int i_ = 0; i_ < 4; ++i_)                            \
  _Pragma("unroll") for (int n_ = 0; n_ < 2; ++n_)                            \
      acc[(ih) * 4 + i_][(nh) * 2 + n_] =                                     \
          __builtin_amdgcn_mfma_f32_16x16x32_bf16(                            \
              af[i_][k_], B[n_][k_], acc[(ih) * 4 + i_][(nh) * 2 + n_], 0, 0, \
              0);                                                             \
  __builtin_amdgcn_s_setprio(0)

template <typename CT>
__global__ __launch_bounds__(512, 2) void k_gemm256(
    const bf16* __restrict__ A, const bf16* __restrict__ Bt, CT* __restrict__ C,
    int NT) {
  const int b0 = blockIdx.x;
  const int swz = (b0 & 7) * 32 + (b0 >> 3);
  const int mb = swz >> 2, nb = swz & 3;

  const int tid = threadIdx.x, lane = tid & 63, wid = tid >> 6;
  const int wr = wid >> 2, wc = wid & 3;
  const int x = lane & 15, g = lane >> 4;
  __shared__ bf16 Asl[2][16384];
  __shared__ bf16 Bsl[2][16384];

  const bf16* Ab = A + (long)mb * 256 * 1024;
  const bf16* Bb = Bt + (long)nb * 256 * 1024;
  const int srow8 = lane >> 3;
  const int skk = (((lane & 7) ^ srow8) << 3);

  auto stage = [&](int buf, int T, int j) {
    const bf16* src = (j < 2) ? Ab : Bb;
    bf16* db = ((j < 2) ? Asl[buf] : Bsl[buf]) + (j & 1) * 8192;
    const long ko = (long)T * 64 + skk;
#pragma unroll
    for (int i2 = 0; i2 < 2; ++i2) {
      const int c = wid * 2 + i2;
      GLL(src + (long)((j & 1) * 128 + c * 8 + srow8) * 1024 + ko, db + c * 512);
    }
  };
  auto ldaf = [&](int buf, int i, int s) {
    const int r = wr * 128 + i * 16 + x;
    return *reinterpret_cast<const bf16x8*>(
        reinterpret_cast<const char*>(Asl[buf]) + r * 128 +
        ((((s << 2) | g) ^ (r & 7)) << 4));
  };
  auto ldbf = [&](int buf, int n, int s) {
    const int c = wc * 64 + n * 16 + x;
    return *reinterpret_cast<const bf16x8*>(
        reinterpret_cast<const char*>(Bsl[buf]) + c * 128 +
        ((((s << 2) | g) ^ (c & 7)) << 4));
  };

  f32x4 acc[8][4] = {};
  bf16x8 af[4][2], bn01[2][2], bn23[2][2];

  stage(0, 0, 0); stage(0, 0, 1); stage(0, 0, 2); stage(0, 0, 3);
  stage(1, 1, 2); stage(1, 1, 3);
  VMC4;

  const int nit = NT >> 1;
  for (int it = 0; it < nit; ++it) {
    const int T = 2 * it;
    const int Tp1 = T + 1, Tp2 = (T + 2) % NT, Tp3 = (T + 3) % NT;
    // ph1 (publish T -> buf0)
    BARR; SB0;
    RDA(0, 0); RDB(0, 0, bn01);
    LGKM0;
    MM(0, 0, bn01);
    RDB(0, 1, bn23); stage(1, Tp1, 0);
    // ph2
    BARR; SB0; LGKM0;
    MM(0, 1, bn23);
    RDA(0, 1); stage(1, Tp1, 1);
    // ph3
    BARR; SB0; LGKM0;
    MM(1, 0, bn01);
    stage(0, Tp2, 2);
    // ph4
    BARR; SB0; LGKM0;
    MM(1, 1, bn23);
    stage(0, Tp2, 3);
    VMC4;
    // ph5 (publish T+1 -> buf1)
    BARR; SB0;
    RDA(1, 0); RDB(1, 0, bn01);
    LGKM0;
    MM(0, 0, bn01);
    RDB(1, 1, bn23); stage(0, Tp2, 0);
    // ph6
    BARR; SB0; LGKM0;
    MM(0, 1, bn23);
    RDA(1, 1); stage(0, Tp2, 1);
    // ph7
    BARR; SB0; LGKM0;
    MM(1, 0, bn01);
    stage(1, Tp3, 2);
    // ph8
    BARR; SB0; LGKM0;
    MM(1, 1, bn23);
    stage(1, Tp3, 3);
    VMC4;
  }

  const long row0 = (long)mb * 256 + wr * 128 + (g << 2);
  const int col0 = nb * 256 + wc * 64 + x;
#pragma unroll
  for (int i = 0; i < 8; ++i)
#pragma unroll
    for (int r = 0; r < 4; ++r)
#pragma unroll
      for (int n = 0; n < 4; ++n)
        C[(row0 + i * 16 + r) * 1024 + (col0 + n * 16)] = (CT)acc[i][n][r];
}

// ------------------------------------ split-K partial reduce (4 bf16 -> 1 bf16)
__global__ __launch_bounds__(256) void k_red4b(const bf16* __restrict__ p,
                                               bf16* __restrict__ out) {
  const int i = blockIdx.x * 256 + threadIdx.x;
  const int SL = 512 * 1024;
  const int b = (i * 4) / SL;
  const int e = (i * 4) % SL;
  const bf16* base = p + (size_t)b * 4 * SL + e;
  bf16x4 s0 = *reinterpret_cast<const bf16x4*>(base);
  bf16x4 s1 = *reinterpret_cast<const bf16x4*>(base + SL);
  bf16x4 s2 = *reinterpret_cast<const bf16x4*>(base + 2 * SL);
  bf16x4 s3 = *reinterpret_cast<const bf16x4*>(base + 3 * SL);
  bf16x4 o;
#pragma unroll
  for (int j = 0; j < 4; ++j)
    o[j] = (bf16)((float)s0[j] + (float)s1[j] + (float)s2[j] + (float)s3[j]);
  *reinterpret_cast<bf16x4*>(out + (size_t)b * SL + e) = o;
}

// ------------------------------------ split-K pair reduce (2 bf16 -> 1 bf16)
// slabs of SL = 256*1024 elems; out slab b = p slab 2b + p slab 2b+1
__global__ __launch_bounds__(256) void k_red2b(const bf16* __restrict__ p,
                                               bf16* __restrict__ out) {
  const int i = blockIdx.x * 256 + threadIdx.x;  // [0, 262144)
  const int SL = 256 * 1024;
  const int b = (i * 4) / SL;
  const int e = (i * 4) % SL;
  const bf16* base = p + (size_t)b * 2 * SL + e;
  bf16x4 s0 = *reinterpret_cast<const bf16x4*>(base);
  bf16x4 s1 = *reinterpret_cast<const bf16x4*>(base + SL);
  bf16x4 o;
#pragma unroll
  for (int j = 0; j < 4; ++j)
    o[j] = (bf16)((float)s0[j] + (float)s1[j]);
  *reinterpret_cast<bf16x4*>(out + (size_t)b * SL + e) = o;
}

// ------------------------------------------------------------- fused attention
// grid (32 lt2, 16 h, 4 b), 512 thr = 8 waves / 128 q-rows per block.
__global__ __launch_bounds__(512) void k_attn(const bf16* __restrict__ q,
                                              const bf16* __restrict__ kc,
                                              const bf16* __restrict__ vT,
                                              bf16* __restrict__ aout) {
  const int lt = blockIdx.x, h = blockIdx.y, b = blockIdx.z;
  const int tid = threadIdx.x, lane = tid & 63, wid = tid >> 6;
  const int x = lane & 15, g = lane >> 4;
  __shared__ bf16 smem[32768];  // 64 KB
  bf16* Ks = smem;
  bf16* Vs = smem + 16384;

  const bf16* kb = kc + ((long)b * 256) * 1024 + h * 64;
#pragma unroll
  for (int it = 0; it < 4; ++it) {
    const int lin = it * 512 + tid;
    const int k = lin >> 3, s = lin & 7;
    const int rel = k & 31;
    const int pk = (k & ~31) | ((rel & 1) << 4) | ((rel >> 3) << 2) | ((rel >> 1) & 3);
    bf16x8 v = *reinterpret_cast<const bf16x8*>(kb + (long)k * 1024 + s * 8);
    *reinterpret_cast<bf16x8*>(reinterpret_cast<char*>(Ks) + pk * 128 +
                               ((s ^ (pk & 7)) << 4)) = v;
  }
  const bf16* vb = vT + (long)b * 1024 * 256 + (long)h * 64 * 256;
#pragma unroll
  for (int it = 0; it < 4; ++it) {
    const int lin = it * 512 + tid;
    const int d = lin >> 5, s = lin & 31;
    bf16x8 v = *reinterpret_cast<const bf16x8*>(vb + (long)d * 256 + s * 8);
    *reinterpret_cast<bf16x8*>(reinterpret_cast<char*>(Vs) + d * 512 +
                               ((s ^ (d & 7)) << 4)) = v;
  }

  const long qrow0 = (long)b * 4096 + lt * 128 + wid * 16;
  const bf16* qb = q + (qrow0 + x) * 1024 + h * 64;
  bf16x8 qf[2];
#pragma unroll
  for (int ks2 = 0; ks2 < 2; ++ks2)
    qf[ks2] = *reinterpret_cast<const bf16x8*>(qb + ks2 * 32 + g * 8);

  __syncthreads();

  f32x4 ln[16] = {};
  __builtin_amdgcn_s_setprio(1);
#pragma unroll
  for (int ks2 = 0; ks2 < 2; ++ks2) {
    const int slot = ks2 * 4 + g;
#pragma unroll
    for (int f = 0; f < 16; ++f) {
      const int row = f * 16 + x;
      bf16x8 kf = *reinterpret_cast<const bf16x8*>(
          reinterpret_cast<const char*>(Ks) + row * 128 + ((slot ^ (row & 7)) << 4));
      ln[f] = __builtin_amdgcn_mfma_f32_16x16x32_bf16(kf, qf[ks2], ln[f], 0, 0, 0);
    }
  }
  __builtin_amdgcn_s_setprio(0);

  float m = -1e30f;
#pragma unroll
  for (int f = 0; f < 16; ++f)
#pragma unroll
    for (int r = 0; r < 4; ++r) m = fmaxf(m, ln[f][r]);
  m = fmaxf(m, __shfl_xor(m, 16, 64));
  m = fmaxf(m, __shfl_xor(m, 32, 64));
  float sum = 0.f;
#pragma unroll
  for (int f = 0; f < 16; ++f)
#pragma unroll
    for (int r = 0; r < 4; ++r) {
      const float p = __expf((ln[f][r] - m) * 0.125f);
      ln[f][r] = p;
      sum += p;
    }
  sum += __shfl_xor(sum, 16, 64);
  sum += __shfl_xor(sum, 32, 64);
  const float inv = 1.f / sum;

  f32x4 oacc[4] = {};
  __builtin_amdgcn_s_setprio(1);
#pragma unroll
  for (int ks = 0; ks < 8; ++ks) {
    bf16x8 pa;
#pragma unroll
    for (int t = 0; t < 4; ++t) {
      pa[2 * t] = (bf16)ln[2 * ks][t];
      pa[2 * t + 1] = (bf16)ln[2 * ks + 1][t];
    }
    const int slot = ks * 4 + g;
#pragma unroll
    for (int nf = 0; nf < 4; ++nf) {
      const int d2 = nf * 16 + x;
      bf16x8 vv = *reinterpret_cast<const bf16x8*>(
          reinterpret_cast<const char*>(Vs) + d2 * 512 + ((slot ^ (d2 & 7)) << 4));
      oacc[nf] = __builtin_amdgcn_mfma_f32_16x16x32_bf16(pa, vv, oacc[nf], 0, 0, 0);
    }
  }
  __builtin_amdgcn_s_setprio(0);

  float invr[4];
#pragma unroll
  for (int r = 0; r < 4; ++r) invr[r] = __shfl(inv, 4 * g + r, 64);
  bf16* ob = aout + (qrow0 + 4 * g) * 1024 + h * 64 + x;
#pragma unroll
  for (int nf = 0; nf < 4; ++nf)
#pragma unroll
    for (int r = 0; r < 4; ++r)
      ob[(long)r * 1024 + nf * 16] = (bf16)(oacc[nf][r] * invr[r]);
}

// --------------------------------------------------------------------- launch
extern "C" void kernel_launch(void* const* d_in, const int* in_sizes, int n_in,
                              void* d_out, int out_size, void* d_ws, size_t ws_size,
                              hipStream_t stream) {
  const float* x  = (const float*)d_in[0];
  const float* Wq = (const float*)d_in[1];
  const float* Wk = (const float*)d_in[2];
  const float* Wv = (const float*)d_in[3];
  const float* Wo = (const float*)d_in[4];
  const float* Pk = (const float*)d_in[5];
  const float* Pv = (const float*)d_in[6];
  char* ws = (char*)d_ws;
  const long MB = 1024L * 1024;
  bf16* xbf = (bf16*)ws;
  bf16* XT  = (bf16*)(ws + 32 * MB);
  bf16* WqT = (bf16*)(ws + 64 * MB);
  bf16* WkT = (bf16*)(ws + 66 * MB);
  bf16* WvT = (bf16*)(ws + 68 * MB);
  bf16* WoT = (bf16*)(ws + 70 * MB);
  bf16* PT  = (bf16*)(ws + 72 * MB);
  bf16* XCp = (bf16*)(ws + 76 * MB);   // 16 MB bf16 XC partials (dead after red4b)
  bf16* kcbp = (bf16*)(ws + 76 * MB);  // 4 MB kcb partials (after XCp dead)
  bf16* vcTp = (bf16*)(ws + 80 * MB);  // 4 MB vcT partials
  bf16* qbf = (bf16*)(ws + 76 * MB);   // 32 MB (after red2b; partials dead)
  bf16* XC  = (bf16*)(ws + 108 * MB);
  bf16* kcb = (bf16*)(ws + 112 * MB);
  bf16* vcT = (bf16*)(ws + 114 * MB);
  bf16* aout = xbf;
  const int BIG = 1 << 30;
  (void)in_sizes; (void)n_in; (void)out_size; (void)ws_size;

  // 1) all casts/transposes, exact flat grid (5632 blocks)
  XP xp;
  for (int b = 0; b < 4; ++b) {
    xp.src[b] = x + (long)b * 4096 * 1024;
    xp.dst[b] = xbf + (long)b * 4096 * 1024;
    xp.dstT[b] = XT + (long)b * 1024 * 4096;
    xp.R[b] = 4096; xp.C[b] = 1024;
  }
  const float* wsrc[4] = {Wq, Wk, Wv, Wo};
  bf16* wdst[4] = {WqT, WkT, WvT, WoT};
  for (int i = 0; i < 4; ++i) {
    xp.src[4 + i] = wsrc[i];
    xp.dst[4 + i] = nullptr;
    xp.dstT[4 + i] = wdst[i];
    xp.R[4 + i] = 1024; xp.C[4 + i] = 1024;
  }
  xp.src[8] = Pk; xp.dst[8] = nullptr; xp.dstT[8] = PT;
  xp.R[8] = 4096; xp.C[8] = 256;
  xp.src[9] = Pv; xp.dst[9] = nullptr; xp.dstT[9] = PT + 256 * 4096;
  xp.R[9] = 4096; xp.C[9] = 256;
  k_xpose<<<dim3(5632), 256, 0, stream>>>(xp);

  // 2) XC split-K x4 partials (bf16) + reduce
  k_gemm_nt<bf16><<<dim3(4, 8, 16), 256, 0, stream>>>(
      PT, XT, XT, XCp, 4096, 4096, 1024, 1024, 0, 1024L * 4096, 512L * 1024, 4, 1024,
      BIG, XCp, 0, 1024, BIG);
  k_red4b<<<dim3(2048), 256, 0, stream>>>(XCp, XC);

  // 3) kc/vcT split-K x2: z = b*2 + kc, K-chunk 512; partials -> kcbp/vcTp
  //    (XCp region is dead after red4b; qbf not yet written)
  k_gemm_nt<bf16><<<dim3(4, 8, 8), 256, 0, stream>>>(
      XC, WkT, WvT, kcbp, 1024, 1024, 1024, 512, 512L * 1024, 0, 256L * 1024, 2, 512,
      2, vcTp, 1024L * 256, 256, 2);
  k_red2b<<<dim3(1024), 256, 0, stream>>>(kcbp, kcb);
  k_red2b<<<dim3(1024), 256, 0, stream>>>(vcTp, vcT);

  // 4) Q = x @ Wq   (8-phase 256^2 kernel, NT = 16; overwrites partial region)
  k_gemm256<bf16><<<dim3(256), 512, 0, stream>>>(xbf, WqT, qbf, 16);

  // 5) attention
  k_attn<<<dim3(32, 16, 4), 512, 0, stream>>>(qbf, kcb, vcT, aout);

  // 6) out = aout @ Wo (fp32 out)
  k_gemm256<float><<<dim3(256), 512, 0, stream>>>(aout, WoT, (float*)d_out, 16);
}